// Round 7
// baseline (239.142 us; speedup 1.0000x reference)
//
#include <hip/hip_runtime.h>

typedef short  short4v __attribute__((ext_vector_type(4)));
typedef short  short8v __attribute__((ext_vector_type(8)));
typedef __bf16 bf16x8  __attribute__((ext_vector_type(8)));
typedef float  f32x4   __attribute__((ext_vector_type(4)));
typedef float  float4v __attribute__((ext_vector_type(4)));

__device__ __forceinline__ short f2bf(float f) {
  unsigned u = __builtin_bit_cast(unsigned, f);
  u += 0x7fffu + ((u >> 16) & 1u);   // RNE
  return (short)(u >> 16);
}
__device__ __forceinline__ float bf2f(short h) {
  unsigned u = ((unsigned)(unsigned short)h) << 16;
  return __builtin_bit_cast(float, u);
}
__device__ __forceinline__ bf16x8 ld8(const short* p) {
  return __builtin_bit_cast(bf16x8, *reinterpret_cast<const short8v*>(p));
}

// ---------- fp32 -> bf16 convert ----------
__global__ __launch_bounds__(256) void k_cvt(const float* __restrict__ in,
                                             short* __restrict__ out, int n4) {
  int i = blockIdx.x * 256 + threadIdx.x;
  if (i >= n4) return;
  float4v v = *reinterpret_cast<const float4v*>(in + (long)i * 4);
  short4v o;
  o[0] = f2bf(v[0]); o[1] = f2bf(v[1]); o[2] = f2bf(v[2]); o[3] = f2bf(v[3]);
  *reinterpret_cast<short4v*>(out + (long)i * 4) = o;
}

// transposed converts (z selects): Wk->wkT, Wq->wqT, Wv->wvT  (1024x1024)
__global__ __launch_bounds__(256) void k_cvtT(const float* __restrict__ i0,
    const float* __restrict__ i1, const float* __restrict__ i2,
    short* __restrict__ o0, short* __restrict__ o1, short* __restrict__ o2) {
  const float* in = blockIdx.z == 0 ? i0 : blockIdx.z == 1 ? i1 : i2;
  short* out = blockIdx.z == 0 ? o0 : blockIdx.z == 1 ? o1 : o2;
  __shared__ float tile[16][17];
  const int lx = threadIdx.x & 15, ly = threadIdx.x >> 4;
  const int bx = blockIdx.x << 4, by = blockIdx.y << 4;
  tile[ly][lx] = in[(long)(by + ly) * 1024 + bx + lx];
  __syncthreads();
  out[(long)(bx + ly) * 1024 + by + lx] = f2bf(tile[lx][ly]);
}

// column matvec: o[d] = sum_e W[e,d] * v[e]   (bvec = Wk^T * bq)
__global__ __launch_bounds__(256) void k_colvec(const float* __restrict__ W,
    const float* __restrict__ v, float* __restrict__ o) {
  const int d = blockIdx.x * 256 + threadIdx.x;
  float s = 0.f;
  for (int e = 0; e < 1024; ++e) s += W[(long)e * 1024 + d] * v[e];
  o[d] = s;
}

// row matvec: o[r] = sum_e W[r,e] * v[e]   (bv' = Wo * bv)
__global__ __launch_bounds__(256) void k_matvec(const float* __restrict__ W,
    const float* __restrict__ v, float* __restrict__ o) {
  const int row = blockIdx.x * 4 + (threadIdx.x >> 6), lane = threadIdx.x & 63;
  float s = 0.f;
#pragma unroll
  for (int j = 0; j < 16; ++j)
    s += W[(long)row * 1024 + j * 64 + lane] * v[j * 64 + lane];
#pragma unroll
  for (int off = 32; off; off >>= 1) s += __shfl_xor(s, off);
  if (lane == 0) o[row] = s;
}

// row dots vs bf16 matrix: o[i] = sum_d x[i,d]*v[d]   (w = x * bvec)
__global__ __launch_bounds__(256) void k_rowdot(const short* __restrict__ x,
    const float* __restrict__ v, float* __restrict__ o) {
  const int row = blockIdx.x * 4 + (threadIdx.x >> 6), lane = threadIdx.x & 63;
  const short* xr = x + (long)row * 1024 + lane * 16;
  short8v a0 = *reinterpret_cast<const short8v*>(xr);
  short8v a1 = *reinterpret_cast<const short8v*>(xr + 8);
  float s = 0.f;
#pragma unroll
  for (int j = 0; j < 8; ++j) s += bf2f(a0[j]) * v[lane * 16 + j];
#pragma unroll
  for (int j = 0; j < 8; ++j) s += bf2f(a1[j]) * v[lane * 16 + 8 + j];
#pragma unroll
  for (int off = 32; off; off >>= 1) s += __shfl_xor(s, off);
  if (lane == 0) o[row] = s;
}

// ---------- m97-core GEMM (single-buffer, R1-measured): C = A[M,K]*B[N,K]^T ----
// 128x128 tile, 256 thr = 4 waves (2x2), 4x4 16x16x32 frags/wave, BK=64,
// 32KB LDS -> 3 blocks/CU implicit wave overlap (m114). Strided lda/ldb.
// MODE 0: bf16 out, no bias
// MODE 5: bf16 out + row-bias b0p[row]
// MODE 3: exp epilogue: e = exp((acc + w[col])/32), bf16 out + psum (b1p)
// MODE 4: f32 out + col-bias b0p, row-scale 1/L from psum (b1p)
template <int MODE>
__global__ __launch_bounds__(256, 3) void k_gemm(
    const short* __restrict__ A, const short* __restrict__ B,
    const float* __restrict__ b0p, float* __restrict__ b1p,
    void* __restrict__ C0,
    int K, int lda, int ldb, long sA, long sB, long sC, int ldC) {
  __shared__ __align__(16) short lsA[128 * 64];
  __shared__ __align__(16) short lsB[128 * 64];
  __shared__ float invL[128];
  const int tid = threadIdx.x;
  const int lane = tid & 63, wid = tid >> 6;
  const int wr = wid >> 1, wc = wid & 1;
  const int fr = lane & 15, fq = lane >> 4;
  const int bm = blockIdx.x * 128, bn = blockIdx.y * 128;
  const short* Ab = A + (long)blockIdx.z * sA;
  const short* Bb = B + (long)blockIdx.z * sB;

  if constexpr (MODE == 4) {
    if (tid < 128) {
      const float* pr = b1p + ((long)blockIdx.z * 2048 + bm + tid) * 32;
      float s = 0.f;
#pragma unroll
      for (int j = 0; j < 32; ++j) s += pr[j];
      invL[tid] = 1.0f / s;
    }
  }

  f32x4 acc[4][4] = {};

  for (int kt = 0; kt < K; kt += 64) {
    __syncthreads();
#pragma unroll
    for (int c = 0; c < 4; ++c) {
      const int idx = c * 256 + tid;
      const int row = idx >> 3, colh = (idx & 7) << 3;
      const short* ga = Ab + (long)(bm + row) * lda + kt + colh;
      const short* gb = Bb + (long)(bn + row) * ldb + kt + colh;
      __builtin_amdgcn_global_load_lds(
          (const __attribute__((address_space(1))) void*)ga,
          (__attribute__((address_space(3))) void*)&lsA[idx * 8], 16, 0, 0);
      __builtin_amdgcn_global_load_lds(
          (const __attribute__((address_space(1))) void*)gb,
          (__attribute__((address_space(3))) void*)&lsB[idx * 8], 16, 0, 0);
    }
    __syncthreads();
#pragma unroll
    for (int ks = 0; ks < 64; ks += 32) {
      bf16x8 a[4], b[4];
#pragma unroll
      for (int m = 0; m < 4; ++m)
        a[m] = ld8(&lsA[(wr * 64 + m * 16 + fr) * 64 + ks + fq * 8]);
#pragma unroll
      for (int n = 0; n < 4; ++n)
        b[n] = ld8(&lsB[(wc * 64 + n * 16 + fr) * 64 + ks + fq * 8]);
#pragma unroll
      for (int m = 0; m < 4; ++m)
#pragma unroll
        for (int n = 0; n < 4; ++n)
          acc[m][n] = __builtin_amdgcn_mfma_f32_16x16x32_bf16(a[m], b[n], acc[m][n], 0, 0, 0);
    }
  }

  // ---- epilogues ----
  if constexpr (MODE == 3) {
    // e = exp((acc + w[col]) / 32), bf16; per-row partial sums -> psum[...][32]
    short* O = (short*)C0 + (long)blockIdx.z * sC;
    float wv[4];
#pragma unroll
    for (int n = 0; n < 4; ++n)
      wv[n] = b0p[(long)blockIdx.z * 2048 + bn + wc * 64 + n * 16 + fr];
#pragma unroll
    for (int m = 0; m < 4; ++m) {
#pragma unroll
      for (int i = 0; i < 4; ++i) {
        const int row = bm + wr * 64 + m * 16 + fq * 4 + i;
        float rs = 0.f;
#pragma unroll
        for (int n = 0; n < 4; ++n) {
          float e = __expf((acc[m][n][i] + wv[n]) * 0.03125f);
          O[(long)row * ldC + bn + wc * 64 + n * 16 + fr] = f2bf(e);
          rs += e;
        }
        rs += __shfl_xor(rs, 1); rs += __shfl_xor(rs, 2);
        rs += __shfl_xor(rs, 4); rs += __shfl_xor(rs, 8);
        if (fr == 0)
          b1p[((long)blockIdx.z * 2048 + row) * 32 + (blockIdx.y << 1) + wc] = rs;
      }
    }
  } else {
#pragma unroll
    for (int n = 0; n < 4; ++n) {
      const int coll = wc * 64 + n * 16 + fr;
#pragma unroll
      for (int m = 0; m < 4; ++m) {
        const int rl0 = wr * 64 + m * 16 + fq * 4;
#pragma unroll
        for (int i = 0; i < 4; ++i) {
          const float vacc = acc[m][n][i];
          const long row = bm + rl0 + i, col = bn + coll;
          if constexpr (MODE == 0) {
            ((short*)C0)[((long)blockIdx.z * sC) + row * ldC + col] = f2bf(vacc);
          } else if constexpr (MODE == 5) {
            ((short*)C0)[row * ldC + col] = f2bf(vacc + b0p[row]);
          } else {  // MODE 4
            float* O = (float*)C0 + (long)blockIdx.z * sC;
            O[row * ldC + col] = vacc * invL[rl0 + i] + b0p[col];
          }
        }
      }
    }
  }
}

// ---------- launcher ----------
extern "C" void kernel_launch(void* const* d_in, const int* in_sizes, int n_in,
                              void* d_out, int out_size, void* d_ws, size_t ws_size,
                              hipStream_t stream) {
  const float* x  = (const float*)d_in[0];
  const float* Wq = (const float*)d_in[1];
  const float* bq = (const float*)d_in[2];
  const float* Wk = (const float*)d_in[3];
  // bk: provably no effect (softmax row-shift invariance) — unused.
  const float* Wv = (const float*)d_in[5];
  const float* bv = (const float*)d_in[6];
  const float* Wo = (const float*)d_in[7];
  const float* bo = (const float*)d_in[8];

  // ws layout: every region fully overwritten before read each call.
  char* ws = (char*)d_ws;
  short* xb   = (short*)ws; ws += 8192L * 1024 * 2;     // x bf16
  short* wkT  = (short*)ws; ws += 1024L * 1024 * 2;     // Wk^T bf16  (A slot 0)
  short* wob  = (short*)ws; ws += 1024L * 1024 * 2;     // Wo bf16    (A slot 1)
  short* wqT  = (short*)ws; ws += 1024L * 1024 * 2;     // Wq^T bf16  (B slot 0)
  short* wvT  = (short*)ws; ws += 1024L * 1024 * 2;     // Wv^T bf16  (B slot 1)
  short* mt   = (short*)ws; ws += 1024L * 1024 * 2;     // Mt = Wk^T*Wq (C slot 0)
  short* wv2  = (short*)ws; ws += 1024L * 1024 * 2;     // Wv''= Wo*Wv (C slot 1)
  short* T    = (short*)ws; ws += 8192L * 1024 * 2;     // T = x*Mt^T
  short* vTp  = (short*)ws; ws += 1024L * 8192 * 2;     // V'^T [e][b*2048+s]
  short* Sc   = (short*)ws; ws += 4L * 2048 * 2048 * 2; // exp-scores
  float* psum = (float*)ws; ws += 4L * 2048 * 32 * 4;   // row partial sums
  float* w8   = (float*)ws; ws += 8192L * 4;            // w[t] = x*(Wk^T bq)
  float* bvec = (float*)ws; ws += 1024L * 4;            // Wk^T * bq
  float* bvp  = (float*)ws; ws += 1024L * 4;            // bv' = Wo * bv

  dim3 b256(256);
  k_cvt<<<8192, b256, 0, stream>>>(x, xb, 2097152);
  k_cvt<<<1024, b256, 0, stream>>>(Wo, wob, 262144);
  k_cvtT<<<dim3(64, 64, 3), b256, 0, stream>>>(Wk, Wq, Wv, wkT, wqT, wvT);
  k_colvec<<<4, b256, 0, stream>>>(Wk, bq, bvec);
  k_matvec<<<256, b256, 0, stream>>>(Wo, bv, bvp);
  k_rowdot<<<2048, b256, 0, stream>>>(xb, bvec, w8);

  // fused tiny GEMMs (z=0: Mt = wkT*wqT^T; z=1: Wv'' = wob*wvT^T)
  k_gemm<0><<<dim3(8, 8, 2), b256, 0, stream>>>(
      wkT, wqT, nullptr, nullptr, mt,
      1024, 1024, 1024, 1024L * 1024, 1024L * 1024, 1024L * 1024, 1024);
  // T = x * Mt^T   (M=8192, N=1024, K=1024)
  k_gemm<0><<<dim3(64, 8, 1), b256, 0, stream>>>(
      xb, mt, nullptr, nullptr, T, 1024, 1024, 1024, 0, 0, 0, 1024);
  // V'^T[e][b*2048+s] = Wv'' * x^T + bv'[e]  (M=1024, N=8192, K=1024)
  k_gemm<5><<<dim3(8, 64, 1), b256, 0, stream>>>(
      wv2, xb, bvp, nullptr, vTp, 1024, 1024, 1024, 0, 0, 0, 8192);
  // exp-scores[b] = exp((T[b]*x[b]^T + w)/32) + psum  (M=N=2048, K=1024)
  k_gemm<3><<<dim3(16, 16, 4), b256, 0, stream>>>(
      T, xb, w8, psum, Sc,
      1024, 1024, 1024, 2048L * 1024, 2048L * 1024, 2048L * 2048, 2048);
  // out = (P_unnorm * V') / L + bo -> fp32 d_out  (M=2048, N=1024, K=2048)
  k_gemm<4><<<dim3(16, 8, 4), b256, 0, stream>>>(
      Sc, vTp, bo, psum, (float*)d_out,
      2048, 2048, 8192, 2048L * 2048, 2048, 2048L * 1024, 1024);
}

// Round 8
// 218.390 us; speedup vs baseline: 1.0950x; 1.0950x over previous
//
#include <hip/hip_runtime.h>

typedef short  short4v __attribute__((ext_vector_type(4)));
typedef short  short8v __attribute__((ext_vector_type(8)));
typedef __bf16 bf16x8  __attribute__((ext_vector_type(8)));
typedef float  f32x4   __attribute__((ext_vector_type(4)));
typedef float  float4v __attribute__((ext_vector_type(4)));

__device__ __forceinline__ short f2bf(float f) {
  unsigned u = __builtin_bit_cast(unsigned, f);
  u += 0x7fffu + ((u >> 16) & 1u);   // RNE
  return (short)(u >> 16);
}
__device__ __forceinline__ float bf2f(short h) {
  unsigned u = ((unsigned)(unsigned short)h) << 16;
  return __builtin_bit_cast(float, u);
}
__device__ __forceinline__ bf16x8 ld8(const short* p) {
  return __builtin_bit_cast(bf16x8, *reinterpret_cast<const short8v*>(p));
}

// ---------- fp32 -> bf16 convert ----------
__global__ __launch_bounds__(256) void k_cvt(const float* __restrict__ in,
                                             short* __restrict__ out, int n4) {
  int i = blockIdx.x * 256 + threadIdx.x;
  if (i >= n4) return;
  float4v v = *reinterpret_cast<const float4v*>(in + (long)i * 4);
  short4v o;
  o[0] = f2bf(v[0]); o[1] = f2bf(v[1]); o[2] = f2bf(v[2]); o[3] = f2bf(v[3]);
  *reinterpret_cast<short4v*>(out + (long)i * 4) = o;
}

// z=0..2: transposed convert (Wk->wkT, Wq->wqT, Wv->wvT); z=3: plain (Wo->wob)
__global__ __launch_bounds__(256) void k_cvtT(const float* __restrict__ i0,
    const float* __restrict__ i1, const float* __restrict__ i2,
    const float* __restrict__ i3, short* __restrict__ o0, short* __restrict__ o1,
    short* __restrict__ o2, short* __restrict__ o3) {
  const int z = blockIdx.z;
  const float* in = z == 0 ? i0 : z == 1 ? i1 : z == 2 ? i2 : i3;
  short* out = z == 0 ? o0 : z == 1 ? o1 : z == 2 ? o2 : o3;
  __shared__ float tile[16][17];
  const int lx = threadIdx.x & 15, ly = threadIdx.x >> 4;
  const int bx = blockIdx.x << 4, by = blockIdx.y << 4;
  float v = in[(long)(by + ly) * 1024 + bx + lx];
  if (z == 3) {  // whole block takes this path: no barrier divergence
    out[(long)(by + ly) * 1024 + bx + lx] = f2bf(v);
    return;
  }
  tile[ly][lx] = v;
  __syncthreads();
  out[(long)(bx + ly) * 1024 + by + lx] = f2bf(tile[lx][ly]);
}

// row matvec (fp32 W): o[r] = sum_e W[r,e] * v[e]   (bv' = Wo * bv)
__global__ __launch_bounds__(256) void k_matvec(const float* __restrict__ W,
    const float* __restrict__ v, float* __restrict__ o) {
  const int row = blockIdx.x * 4 + (threadIdx.x >> 6), lane = threadIdx.x & 63;
  float s = 0.f;
#pragma unroll
  for (int j = 0; j < 16; ++j)
    s += W[(long)row * 1024 + j * 64 + lane] * v[j * 64 + lane];
#pragma unroll
  for (int off = 32; off; off >>= 1) s += __shfl_xor(s, off);
  if (lane == 0) o[row] = s;
}

// row dots vs bf16 matrix: o[i] = sum_d X[i,d]*v[d]
// used for: bvec = wkT rows . bq  (256 blocks), w8 = xb rows . bvec (2048 blocks)
__global__ __launch_bounds__(256) void k_rowdot(const short* __restrict__ X,
    const float* __restrict__ v, float* __restrict__ o) {
  const int row = blockIdx.x * 4 + (threadIdx.x >> 6), lane = threadIdx.x & 63;
  const short* xr = X + (long)row * 1024 + lane * 16;
  short8v a0 = *reinterpret_cast<const short8v*>(xr);
  short8v a1 = *reinterpret_cast<const short8v*>(xr + 8);
  float s = 0.f;
#pragma unroll
  for (int j = 0; j < 8; ++j) s += bf2f(a0[j]) * v[lane * 16 + j];
#pragma unroll
  for (int j = 0; j < 8; ++j) s += bf2f(a1[j]) * v[lane * 16 + 8 + j];
#pragma unroll
  for (int off = 32; off; off >>= 1) s += __shfl_xor(s, off);
  if (lane == 0) o[row] = s;
}

// ---------- m97-core GEMM (single-buffer, measured 634 TF): C = A*B^T ----------
// 128x128 tile, 256 thr = 4 waves (2x2), 4x4 16x16x32 frags/wave, BK=64,
// 32KB LDS -> 3 blocks/CU implicit wave overlap. T1 XCD-swizzle on block ids.
// MODE 0: bf16 out, no bias
// MODE 5: bf16 out + row-bias b0p[row]
// MODE 3: exp epilogue: e = exp((acc + w[col])/32), bf16 out + psum (b1p)
// MODE 4: f32 out + col-bias b0p, row-scale 1/L from psum (b1p)
template <int MODE>
__global__ __launch_bounds__(256, 3) void k_gemm(
    const short* __restrict__ A, const short* __restrict__ B,
    const float* __restrict__ b0p, float* __restrict__ b1p,
    void* __restrict__ C0,
    int K, int lda, int ldb, long sA, long sB, long sC, int ldC) {
  // T1: XCD-aware bijective remap (contiguous logical chunk per XCD)
  int bx, by, bz;
  {
    const int gx = gridDim.x, gy = gridDim.y;
    const int n = gx * gy * gridDim.z;
    int f = blockIdx.x + gx * (blockIdx.y + gy * blockIdx.z);
    int s = (n & 7) ? f : ((f & 7) * (n >> 3) + (f >> 3));
    bx = s % gx; int rem = s / gx; by = rem % gy; bz = rem / gy;
  }
  __shared__ __align__(16) short lsA[128 * 64];
  __shared__ __align__(16) short lsB[128 * 64];
  __shared__ float invL[128];
  const int tid = threadIdx.x;
  const int lane = tid & 63, wid = tid >> 6;
  const int wr = wid >> 1, wc = wid & 1;
  const int fr = lane & 15, fq = lane >> 4;
  const int bm = bx * 128, bn = by * 128;
  const short* Ab = A + (long)bz * sA;
  const short* Bb = B + (long)bz * sB;

  if constexpr (MODE == 4) {
    if (tid < 128) {
      const float* pr = b1p + ((long)bz * 2048 + bm + tid) * 32;
      float s = 0.f;
#pragma unroll
      for (int j = 0; j < 32; ++j) s += pr[j];
      invL[tid] = 1.0f / s;
    }
  }

  f32x4 acc[4][4] = {};

  for (int kt = 0; kt < K; kt += 64) {
    __syncthreads();
#pragma unroll
    for (int c = 0; c < 4; ++c) {
      const int idx = c * 256 + tid;
      const int row = idx >> 3, colh = (idx & 7) << 3;
      const short* ga = Ab + (long)(bm + row) * lda + kt + colh;
      const short* gb = Bb + (long)(bn + row) * ldb + kt + colh;
      __builtin_amdgcn_global_load_lds(
          (const __attribute__((address_space(1))) void*)ga,
          (__attribute__((address_space(3))) void*)&lsA[idx * 8], 16, 0, 0);
      __builtin_amdgcn_global_load_lds(
          (const __attribute__((address_space(1))) void*)gb,
          (__attribute__((address_space(3))) void*)&lsB[idx * 8], 16, 0, 0);
    }
    __syncthreads();
#pragma unroll
    for (int ks = 0; ks < 64; ks += 32) {
      bf16x8 a[4], b[4];
#pragma unroll
      for (int m = 0; m < 4; ++m)
        a[m] = ld8(&lsA[(wr * 64 + m * 16 + fr) * 64 + ks + fq * 8]);
#pragma unroll
      for (int n = 0; n < 4; ++n)
        b[n] = ld8(&lsB[(wc * 64 + n * 16 + fr) * 64 + ks + fq * 8]);
#pragma unroll
      for (int m = 0; m < 4; ++m)
#pragma unroll
        for (int n = 0; n < 4; ++n)
          acc[m][n] = __builtin_amdgcn_mfma_f32_16x16x32_bf16(a[m], b[n], acc[m][n], 0, 0, 0);
    }
  }

  // ---- epilogues ----
  if constexpr (MODE == 3) {
    short* O = (short*)C0 + (long)bz * sC;
    float wv[4];
#pragma unroll
    for (int n = 0; n < 4; ++n)
      wv[n] = b0p[(long)bz * 2048 + bn + wc * 64 + n * 16 + fr];
#pragma unroll
    for (int m = 0; m < 4; ++m) {
#pragma unroll
      for (int i = 0; i < 4; ++i) {
        const int row = bm + wr * 64 + m * 16 + fq * 4 + i;
        float rs = 0.f;
#pragma unroll
        for (int n = 0; n < 4; ++n) {
          float e = __expf((acc[m][n][i] + wv[n]) * 0.03125f);
          O[(long)row * ldC + bn + wc * 64 + n * 16 + fr] = f2bf(e);
          rs += e;
        }
        rs += __shfl_xor(rs, 1); rs += __shfl_xor(rs, 2);
        rs += __shfl_xor(rs, 4); rs += __shfl_xor(rs, 8);
        if (fr == 0)
          b1p[((long)bz * 2048 + row) * 32 + (by << 1) + wc] = rs;
      }
    }
  } else {
#pragma unroll
    for (int n = 0; n < 4; ++n) {
      const int coll = wc * 64 + n * 16 + fr;
#pragma unroll
      for (int m = 0; m < 4; ++m) {
        const int rl0 = wr * 64 + m * 16 + fq * 4;
#pragma unroll
        for (int i = 0; i < 4; ++i) {
          const float vacc = acc[m][n][i];
          const long row = bm + rl0 + i, col = bn + coll;
          if constexpr (MODE == 0) {
            ((short*)C0)[((long)bz * sC) + row * ldC + col] = f2bf(vacc);
          } else if constexpr (MODE == 5) {
            ((short*)C0)[row * ldC + col] = f2bf(vacc + b0p[row]);
          } else {  // MODE 4
            float* O = (float*)C0 + (long)bz * sC;
            O[row * ldC + col] = vacc * invL[rl0 + i] + b0p[col];
          }
        }
      }
    }
  }
}

// ---------- launcher ----------
extern "C" void kernel_launch(void* const* d_in, const int* in_sizes, int n_in,
                              void* d_out, int out_size, void* d_ws, size_t ws_size,
                              hipStream_t stream) {
  const float* x  = (const float*)d_in[0];
  const float* Wq = (const float*)d_in[1];
  const float* bq = (const float*)d_in[2];
  const float* Wk = (const float*)d_in[3];
  // bk: provably no effect (softmax row-shift invariance) — unused.
  const float* Wv = (const float*)d_in[5];
  const float* bv = (const float*)d_in[6];
  const float* Wo = (const float*)d_in[7];
  const float* bo = (const float*)d_in[8];

  // ws layout: every region fully overwritten before read each call.
  char* ws = (char*)d_ws;
  short* xb   = (short*)ws; ws += 8192L * 1024 * 2;     // x bf16
  short* wkT  = (short*)ws; ws += 1024L * 1024 * 2;     // Wk^T bf16  (A slot 0)
  short* wob  = (short*)ws; ws += 1024L * 1024 * 2;     // Wo bf16    (A slot 1)
  short* wqT  = (short*)ws; ws += 1024L * 1024 * 2;     // Wq^T bf16  (B slot 0)
  short* wvT  = (short*)ws; ws += 1024L * 1024 * 2;     // Wv^T bf16  (B slot 1)
  short* mt   = (short*)ws; ws += 1024L * 1024 * 2;     // Mt = Wk^T*Wq (C slot 0)
  short* wv2  = (short*)ws; ws += 1024L * 1024 * 2;     // Wv''= Wo*Wv (C slot 1)
  short* T    = (short*)ws; ws += 8192L * 1024 * 2;     // T = x*Mt^T
  short* vTp  = (short*)ws; ws += 1024L * 8192 * 2;     // V'^T [e][b*2048+s]
  short* Sc   = (short*)ws; ws += 4L * 2048 * 2048 * 2; // exp-scores
  float* psum = (float*)ws; ws += 4L * 2048 * 32 * 4;   // row partial sums
  float* w8   = (float*)ws; ws += 8192L * 4;            // w[t] = x*(Wk^T bq)
  float* bvec = (float*)ws; ws += 1024L * 4;            // Wk^T * bq
  float* bvp  = (float*)ws; ws += 1024L * 4;            // bv' = Wo * bv

  dim3 b256(256);
  k_cvt<<<8192, b256, 0, stream>>>(x, xb, 2097152);
  k_cvtT<<<dim3(64, 64, 4), b256, 0, stream>>>(
      Wk, Wq, Wv, Wo, wkT, wqT, wvT, wob);
  // bvec = Wk^T * bq  (rows of wkT . bq) — parallel, replaces serial colvec
  k_rowdot<<<256, b256, 0, stream>>>(wkT, bq, bvec);
  k_matvec<<<256, b256, 0, stream>>>(Wo, bv, bvp);
  k_rowdot<<<2048, b256, 0, stream>>>(xb, bvec, w8);

  // fused tiny GEMMs (z=0: Mt = wkT*wqT^T; z=1: Wv'' = wob*wvT^T)
  k_gemm<0><<<dim3(8, 8, 2), b256, 0, stream>>>(
      wkT, wqT, nullptr, nullptr, mt,
      1024, 1024, 1024, 1024L * 1024, 1024L * 1024, 1024L * 1024, 1024);
  // T = x * Mt^T   (M=8192, N=1024, K=1024)
  k_gemm<0><<<dim3(64, 8, 1), b256, 0, stream>>>(
      xb, mt, nullptr, nullptr, T, 1024, 1024, 1024, 0, 0, 0, 1024);
  // V'^T[e][b*2048+s] = Wv'' * x^T + bv'[e]  (M=1024, N=8192, K=1024)
  k_gemm<5><<<dim3(8, 64, 1), b256, 0, stream>>>(
      wv2, xb, bvp, nullptr, vTp, 1024, 1024, 1024, 0, 0, 0, 8192);
  // exp-scores[b] = exp((T[b]*x[b]^T + w)/32) + psum  (M=N=2048, K=1024)
  k_gemm<3><<<dim3(16, 16, 4), b256, 0, stream>>>(
      T, xb, w8, psum, Sc,
      1024, 1024, 1024, 2048L * 1024, 2048L * 1024, 2048L * 2048, 2048);
  // out = (P_unnorm * V') / L + bo -> fp32 d_out  (M=2048, N=1024, K=2048)
  k_gemm<4><<<dim3(16, 8, 4), b256, 0, stream>>>(
      Sc, vTp, bo, psum, (float*)d_out,
      2048, 2048, 8192, 2048L * 2048, 2048, 2048L * 1024, 1024);
}

// Round 9
// 212.345 us; speedup vs baseline: 1.1262x; 1.0285x over previous
//
#include <hip/hip_runtime.h>

typedef short  short4v __attribute__((ext_vector_type(4)));
typedef short  short8v __attribute__((ext_vector_type(8)));
typedef __bf16 bf16x8  __attribute__((ext_vector_type(8)));
typedef float  f32x4   __attribute__((ext_vector_type(4)));
typedef float  float4v __attribute__((ext_vector_type(4)));

__device__ __forceinline__ short f2bf(float f) {
  unsigned u = __builtin_bit_cast(unsigned, f);
  u += 0x7fffu + ((u >> 16) & 1u);   // RNE
  return (short)(u >> 16);
}
__device__ __forceinline__ float bf2f(short h) {
  unsigned u = ((unsigned)(unsigned short)h) << 16;
  return __builtin_bit_cast(float, u);
}
__device__ __forceinline__ bf16x8 ld8(const short* p) {
  return __builtin_bit_cast(bf16x8, *reinterpret_cast<const short8v*>(p));
}

// ---------- fp32 -> bf16 convert ----------
__global__ __launch_bounds__(256) void k_cvt(const float* __restrict__ in,
                                             short* __restrict__ out, int n4) {
  int i = blockIdx.x * 256 + threadIdx.x;
  if (i >= n4) return;
  float4v v = *reinterpret_cast<const float4v*>(in + (long)i * 4);
  short4v o;
  o[0] = f2bf(v[0]); o[1] = f2bf(v[1]); o[2] = f2bf(v[2]); o[3] = f2bf(v[3]);
  *reinterpret_cast<short4v*>(out + (long)i * 4) = o;
}

// z=0..2: transposed convert (Wk->wkT, Wq->wqT, Wv->wvT); z=3: plain (Wo->wob)
__global__ __launch_bounds__(256) void k_cvtT(const float* __restrict__ i0,
    const float* __restrict__ i1, const float* __restrict__ i2,
    const float* __restrict__ i3, short* __restrict__ o0, short* __restrict__ o1,
    short* __restrict__ o2, short* __restrict__ o3) {
  const int z = blockIdx.z;
  const float* in = z == 0 ? i0 : z == 1 ? i1 : z == 2 ? i2 : i3;
  short* out = z == 0 ? o0 : z == 1 ? o1 : z == 2 ? o2 : o3;
  __shared__ float tile[16][17];
  const int lx = threadIdx.x & 15, ly = threadIdx.x >> 4;
  const int bx = blockIdx.x << 4, by = blockIdx.y << 4;
  float v = in[(long)(by + ly) * 1024 + bx + lx];
  if (z == 3) {  // whole block takes this path: no barrier divergence
    out[(long)(by + ly) * 1024 + bx + lx] = f2bf(v);
    return;
  }
  tile[ly][lx] = v;
  __syncthreads();
  out[(long)(bx + ly) * 1024 + by + lx] = f2bf(tile[lx][ly]);
}

// fused vector prep, z-routed (256 blocks each):
//   z=0: bvec[r] = wkT rows (bf16) . bq      (= Wk^T * bq)
//   z=1: bvp[r]  = Wo rows (fp32)  . bv      (= Wo * bv)
__global__ __launch_bounds__(256) void k_vecprep(
    const short* __restrict__ wkT, const float* __restrict__ bq,
    const float* __restrict__ Wo, const float* __restrict__ bv,
    float* __restrict__ bvec, float* __restrict__ bvp) {
  const int row = blockIdx.x * 4 + (threadIdx.x >> 6), lane = threadIdx.x & 63;
  float s = 0.f;
  if (blockIdx.z == 0) {
    const short* xr = wkT + (long)row * 1024 + lane * 16;
    short8v a0 = *reinterpret_cast<const short8v*>(xr);
    short8v a1 = *reinterpret_cast<const short8v*>(xr + 8);
#pragma unroll
    for (int j = 0; j < 8; ++j) s += bf2f(a0[j]) * bq[lane * 16 + j];
#pragma unroll
    for (int j = 0; j < 8; ++j) s += bf2f(a1[j]) * bq[lane * 16 + 8 + j];
  } else {
#pragma unroll
    for (int j = 0; j < 16; ++j)
      s += Wo[(long)row * 1024 + j * 64 + lane] * bv[j * 64 + lane];
  }
#pragma unroll
  for (int off = 32; off; off >>= 1) s += __shfl_xor(s, off);
  if (lane == 0) (blockIdx.z == 0 ? bvec : bvp)[row] = s;
}

// row dots vs bf16 matrix: o[i] = sum_d X[i,d]*v[d]   (w8 = xb rows . bvec)
__global__ __launch_bounds__(256) void k_rowdot(const short* __restrict__ X,
    const float* __restrict__ v, float* __restrict__ o) {
  const int row = blockIdx.x * 4 + (threadIdx.x >> 6), lane = threadIdx.x & 63;
  const short* xr = X + (long)row * 1024 + lane * 16;
  short8v a0 = *reinterpret_cast<const short8v*>(xr);
  short8v a1 = *reinterpret_cast<const short8v*>(xr + 8);
  float s = 0.f;
#pragma unroll
  for (int j = 0; j < 8; ++j) s += bf2f(a0[j]) * v[lane * 16 + j];
#pragma unroll
  for (int j = 0; j < 8; ++j) s += bf2f(a1[j]) * v[lane * 16 + 8 + j];
#pragma unroll
  for (int off = 32; off; off >>= 1) s += __shfl_xor(s, off);
  if (lane == 0) o[row] = s;
}

// ---------- m97-core GEMM (single-buffer, measured ~630 TF): C = A*B^T ----------
// 128x128 tile, 256 thr = 4 waves (2x2), 4x4 16x16x32 frags/wave, BK=64,
// 32KB LDS -> 3 blocks/CU implicit wave overlap (m114). No XCD swizzle
// (measured: hurt 6% here, kernels are stall-bound not BW-bound).
// MODE 0: bf16 out, no bias
// MODE 5: bf16 out + row-bias b0p[row]
// MODE 3: exp epilogue: e = exp2((acc + w[col])*c), bf16 out + psum (b1p)
// MODE 4: f32 out + col-bias b0p, row-scale 1/L from psum (b1p)
template <int MODE>
__global__ __launch_bounds__(256, 3) void k_gemm(
    const short* __restrict__ A, const short* __restrict__ B,
    const float* __restrict__ b0p, float* __restrict__ b1p,
    void* __restrict__ C0,
    int K, int lda, int ldb, long sA, long sB, long sC, int ldC) {
  __shared__ __align__(16) short lsA[128 * 64];
  __shared__ __align__(16) short lsB[128 * 64];
  __shared__ float invL[128];
  const int tid = threadIdx.x;
  const int lane = tid & 63, wid = tid >> 6;
  const int wr = wid >> 1, wc = wid & 1;
  const int fr = lane & 15, fq = lane >> 4;
  const int bm = blockIdx.x * 128, bn = blockIdx.y * 128;
  const int bz = blockIdx.z;
  const short* Ab = A + (long)bz * sA;
  const short* Bb = B + (long)bz * sB;

  if constexpr (MODE == 4) {
    if (tid < 128) {
      const float* pr = b1p + ((long)bz * 2048 + bm + tid) * 32;
      float s = 0.f;
#pragma unroll
      for (int j = 0; j < 32; ++j) s += pr[j];
      invL[tid] = 1.0f / s;
    }
  }

  f32x4 acc[4][4] = {};

  for (int kt = 0; kt < K; kt += 64) {
    __syncthreads();
#pragma unroll
    for (int c = 0; c < 4; ++c) {
      const int idx = c * 256 + tid;
      const int row = idx >> 3, colh = (idx & 7) << 3;
      const short* ga = Ab + (long)(bm + row) * lda + kt + colh;
      const short* gb = Bb + (long)(bn + row) * ldb + kt + colh;
      __builtin_amdgcn_global_load_lds(
          (const __attribute__((address_space(1))) void*)ga,
          (__attribute__((address_space(3))) void*)&lsA[idx * 8], 16, 0, 0);
      __builtin_amdgcn_global_load_lds(
          (const __attribute__((address_space(1))) void*)gb,
          (__attribute__((address_space(3))) void*)&lsB[idx * 8], 16, 0, 0);
    }
    __syncthreads();
#pragma unroll
    for (int ks = 0; ks < 64; ks += 32) {
      bf16x8 a[4], b[4];
#pragma unroll
      for (int m = 0; m < 4; ++m)
        a[m] = ld8(&lsA[(wr * 64 + m * 16 + fr) * 64 + ks + fq * 8]);
#pragma unroll
      for (int n = 0; n < 4; ++n)
        b[n] = ld8(&lsB[(wc * 64 + n * 16 + fr) * 64 + ks + fq * 8]);
#pragma unroll
      for (int m = 0; m < 4; ++m)
#pragma unroll
        for (int n = 0; n < 4; ++n)
          acc[m][n] = __builtin_amdgcn_mfma_f32_16x16x32_bf16(a[m], b[n], acc[m][n], 0, 0, 0);
    }
  }

  // ---- epilogues ----
  if constexpr (MODE == 3) {
    constexpr float c = 0.03125f * 1.44269504f;   // 1/32 * log2(e)
    short* O = (short*)C0 + (long)bz * sC;
    float wv[4];
#pragma unroll
    for (int n = 0; n < 4; ++n)
      wv[n] = b0p[(long)bz * 2048 + bn + wc * 64 + n * 16 + fr];
#pragma unroll
    for (int m = 0; m < 4; ++m) {
#pragma unroll
      for (int i = 0; i < 4; ++i) {
        const int row = bm + wr * 64 + m * 16 + fq * 4 + i;
        float rs = 0.f;
#pragma unroll
        for (int n = 0; n < 4; ++n) {
          float e = exp2f((acc[m][n][i] + wv[n]) * c);
          O[(long)row * ldC + bn + wc * 64 + n * 16 + fr] = f2bf(e);
          rs += e;
        }
        rs += __shfl_xor(rs, 1); rs += __shfl_xor(rs, 2);
        rs += __shfl_xor(rs, 4); rs += __shfl_xor(rs, 8);
        if (fr == 0)
          b1p[((long)bz * 2048 + row) * 32 + (blockIdx.y << 1) + wc] = rs;
      }
    }
  } else {
#pragma unroll
    for (int n = 0; n < 4; ++n) {
      const int coll = wc * 64 + n * 16 + fr;
#pragma unroll
      for (int m = 0; m < 4; ++m) {
        const int rl0 = wr * 64 + m * 16 + fq * 4;
#pragma unroll
        for (int i = 0; i < 4; ++i) {
          const float vacc = acc[m][n][i];
          const long row = bm + rl0 + i, col = bn + coll;
          if constexpr (MODE == 0) {
            ((short*)C0)[((long)bz * sC) + row * ldC + col] = f2bf(vacc);
          } else if constexpr (MODE == 5) {
            ((short*)C0)[row * ldC + col] = f2bf(vacc + b0p[row]);
          } else {  // MODE 4
            float* O = (float*)C0 + (long)bz * sC;
            O[row * ldC + col] = vacc * invL[rl0 + i] + b0p[col];
          }
        }
      }
    }
  }
}

// ---------- launcher ----------
extern "C" void kernel_launch(void* const* d_in, const int* in_sizes, int n_in,
                              void* d_out, int out_size, void* d_ws, size_t ws_size,
                              hipStream_t stream) {
  const float* x  = (const float*)d_in[0];
  const float* Wq = (const float*)d_in[1];
  const float* bq = (const float*)d_in[2];
  const float* Wk = (const float*)d_in[3];
  // bk: provably no effect (softmax row-shift invariance) — unused.
  const float* Wv = (const float*)d_in[5];
  const float* bv = (const float*)d_in[6];
  const float* Wo = (const float*)d_in[7];
  const float* bo = (const float*)d_in[8];

  // ws layout: every region fully overwritten before read each call.
  char* ws = (char*)d_ws;
  short* xb   = (short*)ws; ws += 8192L * 1024 * 2;     // x bf16
  short* wkT  = (short*)ws; ws += 1024L * 1024 * 2;     // Wk^T bf16  (A slot 0)
  short* wob  = (short*)ws; ws += 1024L * 1024 * 2;     // Wo bf16    (A slot 1)
  short* wqT  = (short*)ws; ws += 1024L * 1024 * 2;     // Wq^T bf16  (B slot 0)
  short* wvT  = (short*)ws; ws += 1024L * 1024 * 2;     // Wv^T bf16  (B slot 1)
  short* mt   = (short*)ws; ws += 1024L * 1024 * 2;     // Mt = Wk^T*Wq (C slot 0)
  short* wv2  = (short*)ws; ws += 1024L * 1024 * 2;     // Wv''= Wo*Wv (C slot 1)
  short* T    = (short*)ws; ws += 8192L * 1024 * 2;     // T = x*Mt^T
  short* vTp  = (short*)ws; ws += 1024L * 8192 * 2;     // V'^T [e][b*2048+s]
  short* Sc   = (short*)ws; ws += 4L * 2048 * 2048 * 2; // exp-scores
  float* psum = (float*)ws; ws += 4L * 2048 * 32 * 4;   // row partial sums
  float* w8   = (float*)ws; ws += 8192L * 4;            // w[t] = x*(Wk^T bq)
  float* bvec = (float*)ws; ws += 1024L * 4;            // Wk^T * bq
  float* bvp  = (float*)ws; ws += 1024L * 4;            // bv' = Wo * bv

  dim3 b256(256);
  k_cvt<<<8192, b256, 0, stream>>>(x, xb, 2097152);
  k_cvtT<<<dim3(64, 64, 4), b256, 0, stream>>>(
      Wk, Wq, Wv, Wo, wkT, wqT, wvT, wob);
  k_vecprep<<<dim3(256, 1, 2), b256, 0, stream>>>(wkT, bq, Wo, bv, bvec, bvp);
  k_rowdot<<<2048, b256, 0, stream>>>(xb, bvec, w8);

  // fused tiny GEMMs (z=0: Mt = wkT*wqT^T; z=1: Wv'' = wob*wvT^T)
  k_gemm<0><<<dim3(8, 8, 2), b256, 0, stream>>>(
      wkT, wqT, nullptr, nullptr, mt,
      1024, 1024, 1024, 1024L * 1024, 1024L * 1024, 1024L * 1024, 1024);
  // T = x * Mt^T   (M=8192, N=1024, K=1024)
  k_gemm<0><<<dim3(64, 8, 1), b256, 0, stream>>>(
      xb, mt, nullptr, nullptr, T, 1024, 1024, 1024, 0, 0, 0, 1024);
  // V'^T[e][b*2048+s] = Wv'' * x^T + bv'[e]  (M=1024, N=8192, K=1024)
  k_gemm<5><<<dim3(8, 64, 1), b256, 0, stream>>>(
      wv2, xb, bvp, nullptr, vTp, 1024, 1024, 1024, 0, 0, 0, 8192);
  // exp-scores[b] = exp((T[b]*x[b]^T + w)/32) + psum  (M=N=2048, K=1024)
  k_gemm<3><<<dim3(16, 16, 4), b256, 0, stream>>>(
      T, xb, w8, psum, Sc,
      1024, 1024, 1024, 2048L * 1024, 2048L * 1024, 2048L * 2048, 2048);
  // out = (P_unnorm * V') / L + bo -> fp32 d_out  (M=2048, N=1024, K=2048)
  k_gemm<4><<<dim3(16, 8, 4), b256, 0, stream>>>(
      Sc, vTp, bo, psum, (float*)d_out,
      2048, 2048, 8192, 2048L * 2048, 2048, 2048L * 1024, 1024);
}

// Round 10
// 200.816 us; speedup vs baseline: 1.1909x; 1.0574x over previous
//
#include <hip/hip_runtime.h>

typedef short  short4v __attribute__((ext_vector_type(4)));
typedef short  short8v __attribute__((ext_vector_type(8)));
typedef __bf16 bf16x8  __attribute__((ext_vector_type(8)));
typedef float  f32x4   __attribute__((ext_vector_type(4)));
typedef float  float4v __attribute__((ext_vector_type(4)));

__device__ __forceinline__ short f2bf(float f) {
  unsigned u = __builtin_bit_cast(unsigned, f);
  u += 0x7fffu + ((u >> 16) & 1u);   // RNE
  return (short)(u >> 16);
}
__device__ __forceinline__ float bf2f(short h) {
  unsigned u = ((unsigned)(unsigned short)h) << 16;
  return __builtin_bit_cast(float, u);
}
__device__ __forceinline__ bf16x8 ld8(const short* p) {
  return __builtin_bit_cast(bf16x8, *reinterpret_cast<const short8v*>(p));
}

__constant__ const float kExpScale = 0.04508422f;   // log2(e)/32

// ---------- fp32 -> bf16 convert (x) ----------
__global__ __launch_bounds__(256) void k_cvt(const float* __restrict__ in,
                                             short* __restrict__ out, int n4) {
  int i = blockIdx.x * 256 + threadIdx.x;
  if (i >= n4) return;
  float4v v = *reinterpret_cast<const float4v*>(in + (long)i * 4);
  short4v o;
  o[0] = f2bf(v[0]); o[1] = f2bf(v[1]); o[2] = f2bf(v[2]); o[3] = f2bf(v[3]);
  *reinterpret_cast<short4v*>(out + (long)i * 4) = o;
}

// ---------- weight prep, 128x64 tiles, grid (16,8,4) ----------
// z=0: Wk -> wkT (transpose), z=1: Wq -> wqT*c (transpose, exp2-scale fold),
// z=2: Wv -> wvT (transpose), z=3: Wo -> wob (plain convert)
__global__ __launch_bounds__(256) void k_wprep(const float* __restrict__ i0,
    const float* __restrict__ i1, const float* __restrict__ i2,
    const float* __restrict__ i3, short* __restrict__ o0, short* __restrict__ o1,
    short* __restrict__ o2, short* __restrict__ o3) {
  const int z = blockIdx.z;
  const float* in = z == 0 ? i0 : z == 1 ? i1 : z == 2 ? i2 : i3;
  short* out = z == 0 ? o0 : z == 1 ? o1 : z == 2 ? o2 : o3;
  const float sc = (z == 1) ? kExpScale : 1.0f;
  const int tid = threadIdx.x;
  const int c0 = blockIdx.x << 6;   // in-col base (64 wide)
  const int r0 = blockIdx.y << 7;   // in-row base (128 tall)
  if (z == 3) {  // uniform per block
#pragma unroll
    for (int j = 0; j < 8; ++j) {
      int idx = j * 256 + tid;
      int r = idx >> 4, c4 = (idx & 15) << 2;
      float4v v = *reinterpret_cast<const float4v*>(in + (long)(r0 + r) * 1024 + c0 + c4);
      short4v o;
      o[0] = f2bf(v[0]); o[1] = f2bf(v[1]); o[2] = f2bf(v[2]); o[3] = f2bf(v[3]);
      *reinterpret_cast<short4v*>(out + (long)(r0 + r) * 1024 + c0 + c4) = o;
    }
    return;
  }
  __shared__ float tile[128][65];
#pragma unroll
  for (int j = 0; j < 8; ++j) {
    int idx = j * 256 + tid;
    int r = idx >> 4, c4 = (idx & 15) << 2;
    float4v v = *reinterpret_cast<const float4v*>(in + (long)(r0 + r) * 1024 + c0 + c4);
    tile[r][c4 + 0] = v[0] * sc; tile[r][c4 + 1] = v[1] * sc;
    tile[r][c4 + 2] = v[2] * sc; tile[r][c4 + 3] = v[3] * sc;
  }
  __syncthreads();
#pragma unroll
  for (int j = 0; j < 8; ++j) {
    int idx = j * 256 + tid;
    int rO = idx >> 5, g4 = (idx & 31) << 2;   // out row (=in col), out col group
    short4v o;
    o[0] = f2bf(tile[g4 + 0][rO]); o[1] = f2bf(tile[g4 + 1][rO]);
    o[2] = f2bf(tile[g4 + 2][rO]); o[3] = f2bf(tile[g4 + 3][rO]);
    *reinterpret_cast<short4v*>(out + (long)(c0 + rO) * 1024 + r0 + g4) = o;
  }
}

// fused vector prep, z-routed (256 blocks each):
//   z=0: bvec[r] = c * (wkT rows (bf16) . bq)    (= c * Wk^T bq)
//   z=1: bvp[r]  = Wo rows (fp32) . bv           (= Wo * bv)
__global__ __launch_bounds__(256) void k_vecprep(
    const short* __restrict__ wkT, const float* __restrict__ bq,
    const float* __restrict__ Wo, const float* __restrict__ bv,
    float* __restrict__ bvec, float* __restrict__ bvp) {
  const int row = blockIdx.x * 4 + (threadIdx.x >> 6), lane = threadIdx.x & 63;
  float s = 0.f;
  if (blockIdx.z == 0) {
    const short* xr = wkT + (long)row * 1024 + lane * 16;
    short8v a0 = *reinterpret_cast<const short8v*>(xr);
    short8v a1 = *reinterpret_cast<const short8v*>(xr + 8);
#pragma unroll
    for (int j = 0; j < 8; ++j) s += bf2f(a0[j]) * bq[lane * 16 + j];
#pragma unroll
    for (int j = 0; j < 8; ++j) s += bf2f(a1[j]) * bq[lane * 16 + 8 + j];
    s *= kExpScale;
  } else {
#pragma unroll
    for (int j = 0; j < 16; ++j)
      s += Wo[(long)row * 1024 + j * 64 + lane] * bv[j * 64 + lane];
  }
#pragma unroll
  for (int off = 32; off; off >>= 1) s += __shfl_xor(s, off);
  if (lane == 0) (blockIdx.z == 0 ? bvec : bvp)[row] = s;
}

// ---------- shared m97 GEMM core loop (single-buffer, ~630 TF measured) ----------
// 128x128 tile, 256 thr = 4 waves (2x2), 4x4 16x16x32 frags/wave, BK=64,
// 32KB LDS -> ~3 blocks/CU implicit wave overlap (m114).
__device__ __forceinline__ void gemm_loop(const short* __restrict__ Ab,
    const short* __restrict__ Bb, int K, int lda, int ldb, int bm, int bn,
    f32x4 (&acc)[4][4]) {
  __shared__ __align__(16) short lsA[128 * 64];
  __shared__ __align__(16) short lsB[128 * 64];
  const int tid = threadIdx.x;
  const int lane = tid & 63, wid = tid >> 6;
  const int wr = wid >> 1, wc = wid & 1;
  const int fr = lane & 15, fq = lane >> 4;
  for (int kt = 0; kt < K; kt += 64) {
    __syncthreads();
#pragma unroll
    for (int c = 0; c < 4; ++c) {
      const int idx = c * 256 + tid;
      const int row = idx >> 3, colh = (idx & 7) << 3;
      const short* ga = Ab + (long)(bm + row) * lda + kt + colh;
      const short* gb = Bb + (long)(bn + row) * ldb + kt + colh;
      __builtin_amdgcn_global_load_lds(
          (const __attribute__((address_space(1))) void*)ga,
          (__attribute__((address_space(3))) void*)&lsA[idx * 8], 16, 0, 0);
      __builtin_amdgcn_global_load_lds(
          (const __attribute__((address_space(1))) void*)gb,
          (__attribute__((address_space(3))) void*)&lsB[idx * 8], 16, 0, 0);
    }
    __syncthreads();
#pragma unroll
    for (int ks = 0; ks < 64; ks += 32) {
      bf16x8 a[4], b[4];
#pragma unroll
      for (int m = 0; m < 4; ++m)
        a[m] = ld8(&lsA[(wr * 64 + m * 16 + fr) * 64 + ks + fq * 8]);
#pragma unroll
      for (int n = 0; n < 4; ++n)
        b[n] = ld8(&lsB[(wc * 64 + n * 16 + fr) * 64 + ks + fq * 8]);
#pragma unroll
      for (int m = 0; m < 4; ++m)
#pragma unroll
        for (int n = 0; n < 4; ++n)
          acc[m][n] = __builtin_amdgcn_mfma_f32_16x16x32_bf16(a[m], b[n], acc[m][n], 0, 0, 0);
    }
  }
}

// ---------- k_gemm: MODE 0 bf16 plain; MODE 3 exp2+psum; MODE 4 f32+bias+1/L ----
template <int MODE>
__global__ __launch_bounds__(256, 3) void k_gemm(
    const short* __restrict__ A, const short* __restrict__ B,
    const float* __restrict__ b0p, float* __restrict__ b1p,
    void* __restrict__ C0,
    int K, int lda, int ldb, long sA, long sB, long sC, int ldC) {
  __shared__ float invL[128];
  const int tid = threadIdx.x;
  const int lane = tid & 63, wid = tid >> 6;
  const int wr = wid >> 1, wc = wid & 1;
  const int fr = lane & 15, fq = lane >> 4;
  const int bm = blockIdx.x * 128, bn = blockIdx.y * 128;
  const int bz = blockIdx.z;

  if constexpr (MODE == 4) {
    if (tid < 128) {
      const float* pr = b1p + ((long)bz * 2048 + bm + tid) * 32;
      float s = 0.f;
#pragma unroll
      for (int j = 0; j < 32; ++j) s += pr[j];
      invL[tid] = 1.0f / s;
    }
  }

  f32x4 acc[4][4] = {};
  gemm_loop(A + (long)bz * sA, B + (long)bz * sB, K, lda, ldb, bm, bn, acc);

  if constexpr (MODE == 3) {
    // e = exp2(acc + w'[col])  (scale pre-folded into T and w'), + row psum
    short* O = (short*)C0 + (long)bz * sC;
    float wv[4];
#pragma unroll
    for (int n = 0; n < 4; ++n)
      wv[n] = b0p[(long)bz * 2048 + bn + wc * 64 + n * 16 + fr];
#pragma unroll
    for (int m = 0; m < 4; ++m) {
#pragma unroll
      for (int i = 0; i < 4; ++i) {
        const int row = bm + wr * 64 + m * 16 + fq * 4 + i;
        float rs = 0.f;
#pragma unroll
        for (int n = 0; n < 4; ++n) {
          float e = exp2f(acc[m][n][i] + wv[n]);
          O[(long)row * ldC + bn + wc * 64 + n * 16 + fr] = f2bf(e);
          rs += e;
        }
        rs += __shfl_xor(rs, 1); rs += __shfl_xor(rs, 2);
        rs += __shfl_xor(rs, 4); rs += __shfl_xor(rs, 8);
        if (fr == 0)
          b1p[((long)bz * 2048 + row) * 32 + (blockIdx.y << 1) + wc] = rs;
      }
    }
  } else {
#pragma unroll
    for (int n = 0; n < 4; ++n) {
      const int coll = wc * 64 + n * 16 + fr;
#pragma unroll
      for (int m = 0; m < 4; ++m) {
        const int rl0 = wr * 64 + m * 16 + fq * 4;
#pragma unroll
        for (int i = 0; i < 4; ++i) {
          const float vacc = acc[m][n][i];
          const long row = bm + rl0 + i, col = bn + coll;
          if constexpr (MODE == 0) {
            ((short*)C0)[((long)bz * sC) + row * ldC + col] = f2bf(vacc);
          } else {  // MODE 4
            float* O = (float*)C0 + (long)bz * sC;
            O[row * ldC + col] = vacc * invL[rl0 + i] + b0p[col];
          }
        }
      }
    }
  }
}

// ---------- merged mid-stage launch, grid (64,8,3) ----------
// z=0: T = x*Mt^T (bf16, no bias)          [bm=bx*128, bn=by*128, ldC=1024]
// z=1: V'^T = Wv''*x^T + bv' (bf16 rowbias) [bm=by*128, bn=bx*128, ldC=8192]
// z=2: w8[row] = xb rows . bvec (512 blocks x 16 rows)
__global__ __launch_bounds__(256, 3) void k_gemmTV(
    const short* __restrict__ xb, const short* __restrict__ mt,
    const short* __restrict__ wv2, const float* __restrict__ bvp,
    const float* __restrict__ bvec, short* __restrict__ T,
    short* __restrict__ vTp, float* __restrict__ w8) {
  const int tid = threadIdx.x;
  const int lane = tid & 63, wid = tid >> 6;
  if (blockIdx.z == 2) {
    const int rbase = (blockIdx.x * 8 + blockIdx.y) * 16;
#pragma unroll
    for (int rr = 0; rr < 4; ++rr) {
      const int row = rbase + wid * 4 + rr;
      const short* xr = xb + (long)row * 1024 + lane * 16;
      short8v a0 = *reinterpret_cast<const short8v*>(xr);
      short8v a1 = *reinterpret_cast<const short8v*>(xr + 8);
      float s = 0.f;
#pragma unroll
      for (int j = 0; j < 8; ++j) s += bf2f(a0[j]) * bvec[lane * 16 + j];
#pragma unroll
      for (int j = 0; j < 8; ++j) s += bf2f(a1[j]) * bvec[lane * 16 + 8 + j];
#pragma unroll
      for (int off = 32; off; off >>= 1) s += __shfl_xor(s, off);
      if (lane == 0) w8[row] = s;
    }
    return;
  }
  const short *A, *B; const float* bias; short* C; int ldC, bm, bn;
  if (blockIdx.z == 0) {
    A = xb; B = mt; bias = nullptr; C = T; ldC = 1024;
    bm = blockIdx.x * 128; bn = blockIdx.y * 128;
  } else {
    A = wv2; B = xb; bias = bvp; C = vTp; ldC = 8192;
    bm = blockIdx.y * 128; bn = blockIdx.x * 128;
  }
  f32x4 acc[4][4] = {};
  gemm_loop(A, B, 1024, 1024, 1024, bm, bn, acc);
  const int wr = wid >> 1, wc = wid & 1;
  const int fr = lane & 15, fq = lane >> 4;
#pragma unroll
  for (int n = 0; n < 4; ++n) {
    const int col = bn + wc * 64 + n * 16 + fr;
#pragma unroll
    for (int m = 0; m < 4; ++m) {
      const int row0 = bm + wr * 64 + m * 16 + fq * 4;
#pragma unroll
      for (int i = 0; i < 4; ++i) {
        const float bvr = bias ? bias[row0 + i] : 0.f;
        C[(long)(row0 + i) * ldC + col] = f2bf(acc[m][n][i] + bvr);
      }
    }
  }
}

// ---------- launcher ----------
extern "C" void kernel_launch(void* const* d_in, const int* in_sizes, int n_in,
                              void* d_out, int out_size, void* d_ws, size_t ws_size,
                              hipStream_t stream) {
  const float* x  = (const float*)d_in[0];
  const float* Wq = (const float*)d_in[1];
  const float* bq = (const float*)d_in[2];
  const float* Wk = (const float*)d_in[3];
  // bk: provably no effect (softmax row-shift invariance) — unused.
  const float* Wv = (const float*)d_in[5];
  const float* bv = (const float*)d_in[6];
  const float* Wo = (const float*)d_in[7];
  const float* bo = (const float*)d_in[8];

  // ws layout: every region fully overwritten before read each call.
  char* ws = (char*)d_ws;
  short* xb   = (short*)ws; ws += 8192L * 1024 * 2;     // x bf16
  short* wkT  = (short*)ws; ws += 1024L * 1024 * 2;     // Wk^T bf16   (A slot 0)
  short* wob  = (short*)ws; ws += 1024L * 1024 * 2;     // Wo bf16     (A slot 1)
  short* wqT  = (short*)ws; ws += 1024L * 1024 * 2;     // c*Wq^T bf16 (B slot 0)
  short* wvT  = (short*)ws; ws += 1024L * 1024 * 2;     // Wv^T bf16   (B slot 1)
  short* mt   = (short*)ws; ws += 1024L * 1024 * 2;     // Mt = Wk^T*(cWq) (C slot 0)
  short* wv2  = (short*)ws; ws += 1024L * 1024 * 2;     // Wv'' = Wo*Wv    (C slot 1)
  short* T    = (short*)ws; ws += 8192L * 1024 * 2;     // T = x*Mt^T (pre-scaled)
  short* vTp  = (short*)ws; ws += 1024L * 8192 * 2;     // V'^T [e][b*2048+s]
  short* Sc   = (short*)ws; ws += 4L * 2048 * 2048 * 2; // exp-scores
  float* psum = (float*)ws; ws += 4L * 2048 * 32 * 4;   // row partial sums
  float* w8   = (float*)ws; ws += 8192L * 4;            // w' = c * x*(Wk^T bq)
  float* bvec = (float*)ws; ws += 1024L * 4;            // c * Wk^T bq
  float* bvp  = (float*)ws; ws += 1024L * 4;            // bv' = Wo * bv

  dim3 b256(256);
  k_cvt<<<8192, b256, 0, stream>>>(x, xb, 2097152);
  k_wprep<<<dim3(16, 8, 4), b256, 0, stream>>>(
      Wk, Wq, Wv, Wo, wkT, wqT, wvT, wob);
  k_vecprep<<<dim3(256, 1, 2), b256, 0, stream>>>(wkT, bq, Wo, bv, bvec, bvp);

  // fused tiny GEMMs (z=0: Mt = wkT*(c wqT)^T; z=1: Wv'' = wob*wvT^T)
  k_gemm<0><<<dim3(8, 8, 2), b256, 0, stream>>>(
      wkT, wqT, nullptr, nullptr, mt,
      1024, 1024, 1024, 1024L * 1024, 1024L * 1024, 1024L * 1024, 1024);
  // merged: T (z=0), V'^T (z=1), w8 rowdots (z=2)
  k_gemmTV<<<dim3(64, 8, 3), b256, 0, stream>>>(
      xb, mt, wv2, bvp, bvec, T, vTp, w8);
  // exp-scores[b] = exp2(T[b]*x[b]^T + w') + psum  (M=N=2048, K=1024)
  k_gemm<3><<<dim3(16, 16, 4), b256, 0, stream>>>(
      T, xb, w8, psum, Sc,
      1024, 1024, 1024, 2048L * 1024, 2048L * 1024, 2048L * 2048, 2048);
  // out = (P_unnorm * V') / L + bo -> fp32 d_out  (M=2048, N=1024, K=2048)
  k_gemm<4><<<dim3(16, 8, 4), b256, 0, stream>>>(
      Sc, vTp, bo, psum, (float*)d_out,
      2048, 2048, 8192, 2048L * 2048, 2048, 2048L * 1024, 1024);
}

// Round 12
// 197.932 us; speedup vs baseline: 1.2082x; 1.0146x over previous
//
#include <hip/hip_runtime.h>

typedef short  short4v __attribute__((ext_vector_type(4)));
typedef short  short8v __attribute__((ext_vector_type(8)));
typedef __bf16 bf16x8  __attribute__((ext_vector_type(8)));
typedef float  f32x4   __attribute__((ext_vector_type(4)));
typedef float  float4v __attribute__((ext_vector_type(4)));

__device__ __forceinline__ short f2bf(float f) {
  unsigned u = __builtin_bit_cast(unsigned, f);
  u += 0x7fffu + ((u >> 16) & 1u);   // RNE
  return (short)(u >> 16);
}
__device__ __forceinline__ float bf2f(short h) {
  unsigned u = ((unsigned)(unsigned short)h) << 16;
  return __builtin_bit_cast(float, u);
}
__device__ __forceinline__ bf16x8 ld8(const short* p) {
  return __builtin_bit_cast(bf16x8, *reinterpret_cast<const short8v*>(p));
}

__constant__ const float kExpScale = 0.04508422f;   // log2(e)/32

// ---------- fp32 -> bf16 convert (x): 2048 blocks x 4 strided float4 ----------
__global__ __launch_bounds__(256) void k_cvt(const float* __restrict__ in,
                                             short* __restrict__ out) {
  const int i = blockIdx.x * 256 + threadIdx.x;     // group id 0..524287
#pragma unroll
  for (int j = 0; j < 4; ++j) {
    const long g = (long)i + (long)j * 524288;
    float4v v = *reinterpret_cast<const float4v*>(in + g * 4);
    short4v o;
    o[0] = f2bf(v[0]); o[1] = f2bf(v[1]); o[2] = f2bf(v[2]); o[3] = f2bf(v[3]);
    *reinterpret_cast<short4v*>(out + g * 4) = o;
  }
}

// ---------- weight prep, 128x64 tiles, grid (16,8,4) ----------
// z=0: Wk -> wkT (transpose), z=1: Wq -> wqT*c (transpose, exp2-scale fold),
// z=2: Wv -> wvT (transpose), z=3: Wo -> wob (plain convert)
__global__ __launch_bounds__(256) void k_wprep(const float* __restrict__ i0,
    const float* __restrict__ i1, const float* __restrict__ i2,
    const float* __restrict__ i3, short* __restrict__ o0, short* __restrict__ o1,
    short* __restrict__ o2, short* __restrict__ o3) {
  const int z = blockIdx.z;
  const float* in = z == 0 ? i0 : z == 1 ? i1 : z == 2 ? i2 : i3;
  short* out = z == 0 ? o0 : z == 1 ? o1 : z == 2 ? o2 : o3;
  const float sc = (z == 1) ? kExpScale : 1.0f;
  const int tid = threadIdx.x;
  const int c0 = blockIdx.x << 6;
  const int r0 = blockIdx.y << 7;
  if (z == 3) {
#pragma unroll
    for (int j = 0; j < 8; ++j) {
      int idx = j * 256 + tid;
      int r = idx >> 4, c4 = (idx & 15) << 2;
      float4v v = *reinterpret_cast<const float4v*>(in + (long)(r0 + r) * 1024 + c0 + c4);
      short4v o;
      o[0] = f2bf(v[0]); o[1] = f2bf(v[1]); o[2] = f2bf(v[2]); o[3] = f2bf(v[3]);
      *reinterpret_cast<short4v*>(out + (long)(r0 + r) * 1024 + c0 + c4) = o;
    }
    return;
  }
  __shared__ float tile[128][65];
#pragma unroll
  for (int j = 0; j < 8; ++j) {
    int idx = j * 256 + tid;
    int r = idx >> 4, c4 = (idx & 15) << 2;
    float4v v = *reinterpret_cast<const float4v*>(in + (long)(r0 + r) * 1024 + c0 + c4);
    tile[r][c4 + 0] = v[0] * sc; tile[r][c4 + 1] = v[1] * sc;
    tile[r][c4 + 2] = v[2] * sc; tile[r][c4 + 3] = v[3] * sc;
  }
  __syncthreads();
#pragma unroll
  for (int j = 0; j < 8; ++j) {
    int idx = j * 256 + tid;
    int rO = idx >> 5, g4 = (idx & 31) << 2;
    short4v o;
    o[0] = f2bf(tile[g4 + 0][rO]); o[1] = f2bf(tile[g4 + 1][rO]);
    o[2] = f2bf(tile[g4 + 2][rO]); o[3] = f2bf(tile[g4 + 3][rO]);
    *reinterpret_cast<short4v*>(out + (long)(c0 + rO) * 1024 + r0 + g4) = o;
  }
}

// ---------- shared m97 GEMM core loop (single-buffer, measured ~630 TF) ----------
__device__ __forceinline__ void gemm_loop(const short* __restrict__ Ab,
    const short* __restrict__ Bb, int K, int lda, int ldb, int bm, int bn,
    f32x4 (&acc)[4][4]) {
  __shared__ __align__(16) short lsA[128 * 64];
  __shared__ __align__(16) short lsB[128 * 64];
  const int tid = threadIdx.x;
  const int lane = tid & 63, wid = tid >> 6;
  const int wr = wid >> 1, wc = wid & 1;
  const int fr = lane & 15, fq = lane >> 4;
  for (int kt = 0; kt < K; kt += 64) {
    __syncthreads();
#pragma unroll
    for (int c = 0; c < 4; ++c) {
      const int idx = c * 256 + tid;
      const int row = idx >> 3, colh = (idx & 7) << 3;
      const short* ga = Ab + (long)(bm + row) * lda + kt + colh;
      const short* gb = Bb + (long)(bn + row) * ldb + kt + colh;
      __builtin_amdgcn_global_load_lds(
          (const __attribute__((address_space(1))) void*)ga,
          (__attribute__((address_space(3))) void*)&lsA[idx * 8], 16, 0, 0);
      __builtin_amdgcn_global_load_lds(
          (const __attribute__((address_space(1))) void*)gb,
          (__attribute__((address_space(3))) void*)&lsB[idx * 8], 16, 0, 0);
    }
    __syncthreads();
#pragma unroll
    for (int ks = 0; ks < 64; ks += 32) {
      bf16x8 a[4], b[4];
#pragma unroll
      for (int m = 0; m < 4; ++m)
        a[m] = ld8(&lsA[(wr * 64 + m * 16 + fr) * 64 + ks + fq * 8]);
#pragma unroll
      for (int n = 0; n < 4; ++n)
        b[n] = ld8(&lsB[(wc * 64 + n * 16 + fr) * 64 + ks + fq * 8]);
#pragma unroll
      for (int m = 0; m < 4; ++m)
#pragma unroll
        for (int n = 0; n < 4; ++n)
          acc[m][n] = __builtin_amdgcn_mfma_f32_16x16x32_bf16(a[m], b[n], acc[m][n], 0, 0, 0);
    }
  }
}

// ---------- prep2: grid (8,8,3) ----------
// z=0: Mt = wkT*(c wqT)^T   z=1: Wv'' = wob*wvT^T   (128x128 tiles)
// z=2: 64 blocks: vec preps — bvec[16 rows] (bf16 wkT . bq, *c) and
//      bvp[16 rows] (fp32 Wo . bv)
__global__ __launch_bounds__(256, 3) void k_prep2(
    const short* __restrict__ wkT, const short* __restrict__ wqT,
    const short* __restrict__ wob, const short* __restrict__ wvT,
    const float* __restrict__ bq, const float* __restrict__ Wo,
    const float* __restrict__ bv,
    short* __restrict__ mt, short* __restrict__ wv2,
    float* __restrict__ bvec, float* __restrict__ bvp) {
  const int tid = threadIdx.x;
  const int lane = tid & 63, wid = tid >> 6;
  if (blockIdx.z == 2) {
    const int r0 = (blockIdx.y * 8 + blockIdx.x) * 16;
#pragma unroll
    for (int rr = 0; rr < 4; ++rr) {
      const int row = r0 + wid * 4 + rr;
      // bvec
      {
        const short* xr = wkT + (long)row * 1024 + lane * 16;
        short8v a0 = *reinterpret_cast<const short8v*>(xr);
        short8v a1 = *reinterpret_cast<const short8v*>(xr + 8);
        float s = 0.f;
#pragma unroll
        for (int j = 0; j < 8; ++j) s += bf2f(a0[j]) * bq[lane * 16 + j];
#pragma unroll
        for (int j = 0; j < 8; ++j) s += bf2f(a1[j]) * bq[lane * 16 + 8 + j];
#pragma unroll
        for (int off = 32; off; off >>= 1) s += __shfl_xor(s, off);
        if (lane == 0) bvec[row] = s * kExpScale;
      }
      // bvp
      {
        float s = 0.f;
#pragma unroll
        for (int j = 0; j < 16; ++j)
          s += Wo[(long)row * 1024 + j * 64 + lane] * bv[j * 64 + lane];
#pragma unroll
        for (int off = 32; off; off >>= 1) s += __shfl_xor(s, off);
        if (lane == 0) bvp[row] = s;
      }
    }
    return;
  }
  const short* A = blockIdx.z == 0 ? wkT : wob;
  const short* B = blockIdx.z == 0 ? wqT : wvT;
  short* C = blockIdx.z == 0 ? mt : wv2;
  const int bm = blockIdx.x * 128, bn = blockIdx.y * 128;
  f32x4 acc[4][4] = {};
  gemm_loop(A, B, 1024, 1024, 1024, bm, bn, acc);
  const int wr = wid >> 1, wc = wid & 1;
  const int fr = lane & 15, fq = lane >> 4;
#pragma unroll
  for (int n = 0; n < 4; ++n) {
    const int col = bn + wc * 64 + n * 16 + fr;
#pragma unroll
    for (int m = 0; m < 4; ++m) {
      const int row0 = bm + wr * 64 + m * 16 + fq * 4;
#pragma unroll
      for (int i = 0; i < 4; ++i)
        C[(long)(row0 + i) * 1024 + col] = f2bf(acc[m][n][i]);
    }
  }
}

// ---------- k_gemm: MODE 3 exp2+psum; MODE 4 f32+bias+1/L ----------
template <int MODE>
__global__ __launch_bounds__(256, 3) void k_gemm(
    const short* __restrict__ A, const short* __restrict__ B,
    const float* __restrict__ b0p, float* __restrict__ b1p,
    void* __restrict__ C0,
    int K, int lda, int ldb, long sA, long sB, long sC, int ldC) {
  __shared__ float invL[128];
  const int tid = threadIdx.x;
  const int lane = tid & 63, wid = tid >> 6;
  const int wr = wid >> 1, wc = wid & 1;
  const int fr = lane & 15, fq = lane >> 4;
  const int bm = blockIdx.x * 128, bn = blockIdx.y * 128;
  const int bz = blockIdx.z;

  if constexpr (MODE == 4) {
    // row = tid>>1, half = tid&1; 16 floats each, pair-combined via shfl
    const int row = tid >> 1, half = tid & 1;
    const float* pr = b1p + ((long)bz * 2048 + bm + row) * 32 + half * 16;
    float s = 0.f;
#pragma unroll
    for (int j = 0; j < 4; ++j) {
      float4v v = *reinterpret_cast<const float4v*>(pr + j * 4);
      s += v[0] + v[1] + v[2] + v[3];
    }
    s += __shfl_xor(s, 1);
    if (half == 0) invL[row] = 1.0f / s;
  }

  f32x4 acc[4][4] = {};
  gemm_loop(A + (long)bz * sA, B + (long)bz * sB, K, lda, ldb, bm, bn, acc);

  if constexpr (MODE == 3) {
    short* O = (short*)C0 + (long)bz * sC;
    float wv[4];
#pragma unroll
    for (int n = 0; n < 4; ++n)
      wv[n] = b0p[(long)bz * 2048 + bn + wc * 64 + n * 16 + fr];
#pragma unroll
    for (int m = 0; m < 4; ++m) {
#pragma unroll
      for (int i = 0; i < 4; ++i) {
        const int row = bm + wr * 64 + m * 16 + fq * 4 + i;
        float rs = 0.f;
#pragma unroll
        for (int n = 0; n < 4; ++n) {
          float e = exp2f(acc[m][n][i] + wv[n]);
          O[(long)row * ldC + bn + wc * 64 + n * 16 + fr] = f2bf(e);
          rs += e;
        }
        rs += __shfl_xor(rs, 1); rs += __shfl_xor(rs, 2);
        rs += __shfl_xor(rs, 4); rs += __shfl_xor(rs, 8);
        if (fr == 0)
          b1p[((long)bz * 2048 + row) * 32 + (blockIdx.y << 1) + wc] = rs;
      }
    }
  } else {
#pragma unroll
    for (int n = 0; n < 4; ++n) {
      const int coll = wc * 64 + n * 16 + fr;
#pragma unroll
      for (int m = 0; m < 4; ++m) {
        const int rl0 = wr * 64 + m * 16 + fq * 4;
#pragma unroll
        for (int i = 0; i < 4; ++i) {
          const long row = bm + rl0 + i, col = bn + coll;
          float* O = (float*)C0 + (long)bz * sC;
          O[row * ldC + col] = acc[m][n][i] * invL[rl0 + i] + b0p[col];
        }
      }
    }
  }
}

// ---------- merged mid-stage launch, grid (64,8,3) ----------
// z=0: T = x*Mt^T    z=1: V'^T = Wv''*x^T + bv'    z=2: w8 rowdots
__global__ __launch_bounds__(256, 3) void k_gemmTV(
    const short* __restrict__ xb, const short* __restrict__ mt,
    const short* __restrict__ wv2, const float* __restrict__ bvp,
    const float* __restrict__ bvec, short* __restrict__ T,
    short* __restrict__ vTp, float* __restrict__ w8) {
  const int tid = threadIdx.x;
  const int lane = tid & 63, wid = tid >> 6;
  if (blockIdx.z == 2) {
    const int rbase = (blockIdx.x * 8 + blockIdx.y) * 16;
#pragma unroll
    for (int rr = 0; rr < 4; ++rr) {
      const int row = rbase + wid * 4 + rr;
      const short* xr = xb + (long)row * 1024 + lane * 16;
      short8v a0 = *reinterpret_cast<const short8v*>(xr);
      short8v a1 = *reinterpret_cast<const short8v*>(xr + 8);
      float s = 0.f;
#pragma unroll
      for (int j = 0; j < 8; ++j) s += bf2f(a0[j]) * bvec[lane * 16 + j];
#pragma unroll
      for (int j = 0; j < 8; ++j) s += bf2f(a1[j]) * bvec[lane * 16 + 8 + j];
#pragma unroll
      for (int off = 32; off; off >>= 1) s += __shfl_xor(s, off);
      if (lane == 0) w8[row] = s;
    }
    return;
  }
  const short *A, *B; const float* bias; short* C; int ldC, bm, bn;
  if (blockIdx.z == 0) {
    A = xb; B = mt; bias = nullptr; C = T; ldC = 1024;
    bm = blockIdx.x * 128; bn = blockIdx.y * 128;
  } else {
    A = wv2; B = xb; bias = bvp; C = vTp; ldC = 8192;
    bm = blockIdx.y * 128; bn = blockIdx.x * 128;
  }
  f32x4 acc[4][4] = {};
  gemm_loop(A, B, 1024, 1024, 1024, bm, bn, acc);
  const int wr = wid >> 1, wc = wid & 1;
  const int fr = lane & 15, fq = lane >> 4;
#pragma unroll
  for (int n = 0; n < 4; ++n) {
    const int col = bn + wc * 64 + n * 16 + fr;
#pragma unroll
    for (int m = 0; m < 4; ++m) {
      const int row0 = bm + wr * 64 + m * 16 + fq * 4;
#pragma unroll
      for (int i = 0; i < 4; ++i) {
        const float bvr = bias ? bias[row0 + i] : 0.f;
        C[(long)(row0 + i) * ldC + col] = f2bf(acc[m][n][i] + bvr);
      }
    }
  }
}

// ---------- launcher ----------
extern "C" void kernel_launch(void* const* d_in, const int* in_sizes, int n_in,
                              void* d_out, int out_size, void* d_ws, size_t ws_size,
                              hipStream_t stream) {
  const float* x  = (const float*)d_in[0];
  const float* Wq = (const float*)d_in[1];
  const float* bq = (const float*)d_in[2];
  const float* Wk = (const float*)d_in[3];
  // bk: provably no effect (softmax row-shift invariance) — unused.
  const float* Wv = (const float*)d_in[5];
  const float* bv = (const float*)d_in[6];
  const float* Wo = (const float*)d_in[7];
  const float* bo = (const float*)d_in[8];

  // ws layout: every region fully overwritten before read each call.
  char* ws = (char*)d_ws;
  short* xb   = (short*)ws; ws += 8192L * 1024 * 2;     // x bf16
  short* wkT  = (short*)ws; ws += 1024L * 1024 * 2;     // Wk^T bf16
  short* wob  = (short*)ws; ws += 1024L * 1024 * 2;     // Wo bf16
  short* wqT  = (short*)ws; ws += 1024L * 1024 * 2;     // c*Wq^T bf16
  short* wvT  = (short*)ws; ws += 1024L * 1024 * 2;     // Wv^T bf16
  short* mt   = (short*)ws; ws += 1024L * 1024 * 2;     // Mt = Wk^T*(cWq)
  short* wv2  = (short*)ws; ws += 1024L * 1024 * 2;     // Wv'' = Wo*Wv
  short* T    = (short*)ws; ws += 8192L * 1024 * 2;     // T = x*Mt^T (pre-scaled)
  short* vTp  = (short*)ws; ws += 1024L * 8192 * 2;     // V'^T [e][b*2048+s]
  short* Sc   = (short*)ws; ws += 4L * 2048 * 2048 * 2; // exp-scores
  float* psum = (float*)ws; ws += 4L * 2048 * 32 * 4;   // row partial sums
  float* w8   = (float*)ws; ws += 8192L * 4;            // w' = c*x*(Wk^T bq)
  float* bvec = (float*)ws; ws += 1024L * 4;            // c * Wk^T bq
  float* bvp  = (float*)ws; ws += 1024L * 4;            // bv' = Wo * bv

  dim3 b256(256);
  k_cvt<<<2048, b256, 0, stream>>>(x, xb);
  k_wprep<<<dim3(16, 8, 4), b256, 0, stream>>>(
      Wk, Wq, Wv, Wo, wkT, wqT, wvT, wob);
  // tiny GEMMs + vector preps in one launch
  k_prep2<<<dim3(8, 8, 3), b256, 0, stream>>>(
      wkT, wqT, wob, wvT, bq, Wo, bv, mt, wv2, bvec, bvp);
  // merged: T (z=0), V'^T (z=1), w8 rowdots (z=2)
  k_gemmTV<<<dim3(64, 8, 3), b256, 0, stream>>>(
      xb, mt, wv2, bvp, bvec, T, vTp, w8);
  // exp-scores[b] = exp2(T[b]*x[b]^T + w') + psum  (M=N=2048, K=1024)
  k_gemm<3><<<dim3(16, 16, 4), b256, 0, stream>>>(
      T, xb, w8, psum, Sc,
      1024, 1024, 1024, 2048L * 1024, 2048L * 1024, 2048L * 2048, 2048);
  // out = (P_unnorm * V') / L + bo -> fp32 d_out  (M=2048, N=1024, K=2048)
  k_gemm<4><<<dim3(16, 8, 4), b256, 0, stream>>>(
      Sc, vTp, bo, psum, (float*)d_out,
      2048, 2048, 8192, 2048L * 2048, 2048, 2048L * 1024, 1024);
}

// Round 13
// 196.194 us; speedup vs baseline: 1.2189x; 1.0089x over previous
//
#include <hip/hip_runtime.h>

typedef short  short4v __attribute__((ext_vector_type(4)));
typedef short  short8v __attribute__((ext_vector_type(8)));
typedef __bf16 bf16x8  __attribute__((ext_vector_type(8)));
typedef float  f32x4   __attribute__((ext_vector_type(4)));
typedef float  float4v __attribute__((ext_vector_type(4)));

__device__ __forceinline__ short f2bf(float f) {
  unsigned u = __builtin_bit_cast(unsigned, f);
  u += 0x7fffu + ((u >> 16) & 1u);   // RNE
  return (short)(u >> 16);
}
__device__ __forceinline__ float bf2f(short h) {
  unsigned u = ((unsigned)(unsigned short)h) << 16;
  return __builtin_bit_cast(float, u);
}
__device__ __forceinline__ bf16x8 ld8(const short* p) {
  return __builtin_bit_cast(bf16x8, *reinterpret_cast<const short8v*>(p));
}

__constant__ const float kExpScale = 0.04508422f;   // log2(e)/32

// ---------- fp32 -> bf16 convert (x): 2048 blocks x 4 strided float4 ----------
__global__ __launch_bounds__(256) void k_cvt(const float* __restrict__ in,
                                             short* __restrict__ out) {
  const int i = blockIdx.x * 256 + threadIdx.x;
#pragma unroll
  for (int j = 0; j < 4; ++j) {
    const long g = (long)i + (long)j * 524288;
    float4v v = *reinterpret_cast<const float4v*>(in + g * 4);
    short4v o;
    o[0] = f2bf(v[0]); o[1] = f2bf(v[1]); o[2] = f2bf(v[2]); o[3] = f2bf(v[3]);
    *reinterpret_cast<short4v*>(out + g * 4) = o;
  }
}

// ---------- weight prep, 128x64 tiles, grid (16,8,4) ----------
__global__ __launch_bounds__(256) void k_wprep(const float* __restrict__ i0,
    const float* __restrict__ i1, const float* __restrict__ i2,
    const float* __restrict__ i3, short* __restrict__ o0, short* __restrict__ o1,
    short* __restrict__ o2, short* __restrict__ o3) {
  const int z = blockIdx.z;
  const float* in = z == 0 ? i0 : z == 1 ? i1 : z == 2 ? i2 : i3;
  short* out = z == 0 ? o0 : z == 1 ? o1 : z == 2 ? o2 : o3;
  const float sc = (z == 1) ? kExpScale : 1.0f;
  const int tid = threadIdx.x;
  const int c0 = blockIdx.x << 6;
  const int r0 = blockIdx.y << 7;
  if (z == 3) {
#pragma unroll
    for (int j = 0; j < 8; ++j) {
      int idx = j * 256 + tid;
      int r = idx >> 4, c4 = (idx & 15) << 2;
      float4v v = *reinterpret_cast<const float4v*>(in + (long)(r0 + r) * 1024 + c0 + c4);
      short4v o;
      o[0] = f2bf(v[0]); o[1] = f2bf(v[1]); o[2] = f2bf(v[2]); o[3] = f2bf(v[3]);
      *reinterpret_cast<short4v*>(out + (long)(r0 + r) * 1024 + c0 + c4) = o;
    }
    return;
  }
  __shared__ float tile[128][65];
#pragma unroll
  for (int j = 0; j < 8; ++j) {
    int idx = j * 256 + tid;
    int r = idx >> 4, c4 = (idx & 15) << 2;
    float4v v = *reinterpret_cast<const float4v*>(in + (long)(r0 + r) * 1024 + c0 + c4);
    tile[r][c4 + 0] = v[0] * sc; tile[r][c4 + 1] = v[1] * sc;
    tile[r][c4 + 2] = v[2] * sc; tile[r][c4 + 3] = v[3] * sc;
  }
  __syncthreads();
#pragma unroll
  for (int j = 0; j < 8; ++j) {
    int idx = j * 256 + tid;
    int rO = idx >> 5, g4 = (idx & 31) << 2;
    short4v o;
    o[0] = f2bf(tile[g4 + 0][rO]); o[1] = f2bf(tile[g4 + 1][rO]);
    o[2] = f2bf(tile[g4 + 2][rO]); o[3] = f2bf(tile[g4 + 3][rO]);
    *reinterpret_cast<short4v*>(out + (long)(c0 + rO) * 1024 + r0 + g4) = o;
  }
}

// ---------- m97 core loop (4 waves, single-buffer) for prep/TV kernels ----------
__device__ __forceinline__ void gemm_loop(const short* __restrict__ Ab,
    const short* __restrict__ Bb, int K, int lda, int ldb, int bm, int bn,
    f32x4 (&acc)[4][4]) {
  __shared__ __align__(16) short lsA[128 * 64];
  __shared__ __align__(16) short lsB[128 * 64];
  const int tid = threadIdx.x;
  const int lane = tid & 63, wid = tid >> 6;
  const int wr = wid >> 1, wc = wid & 1;
  const int fr = lane & 15, fq = lane >> 4;
  for (int kt = 0; kt < K; kt += 64) {
    __syncthreads();
#pragma unroll
    for (int c = 0; c < 4; ++c) {
      const int idx = c * 256 + tid;
      const int row = idx >> 3, colh = (idx & 7) << 3;
      const short* ga = Ab + (long)(bm + row) * lda + kt + colh;
      const short* gb = Bb + (long)(bn + row) * ldb + kt + colh;
      __builtin_amdgcn_global_load_lds(
          (const __attribute__((address_space(1))) void*)ga,
          (__attribute__((address_space(3))) void*)&lsA[idx * 8], 16, 0, 0);
      __builtin_amdgcn_global_load_lds(
          (const __attribute__((address_space(1))) void*)gb,
          (__attribute__((address_space(3))) void*)&lsB[idx * 8], 16, 0, 0);
    }
    __syncthreads();
#pragma unroll
    for (int ks = 0; ks < 64; ks += 32) {
      bf16x8 a[4], b[4];
#pragma unroll
      for (int m = 0; m < 4; ++m)
        a[m] = ld8(&lsA[(wr * 64 + m * 16 + fr) * 64 + ks + fq * 8]);
#pragma unroll
      for (int n = 0; n < 4; ++n)
        b[n] = ld8(&lsB[(wc * 64 + n * 16 + fr) * 64 + ks + fq * 8]);
#pragma unroll
      for (int m = 0; m < 4; ++m)
#pragma unroll
        for (int n = 0; n < 4; ++n)
          acc[m][n] = __builtin_amdgcn_mfma_f32_16x16x32_bf16(a[m], b[n], acc[m][n], 0, 0, 0);
    }
  }
}

// ---------- prep2: grid (8,8,3) — tiny GEMMs + vector preps ----------
__global__ __launch_bounds__(256, 3) void k_prep2(
    const short* __restrict__ wkT, const short* __restrict__ wqT,
    const short* __restrict__ wob, const short* __restrict__ wvT,
    const float* __restrict__ bq, const float* __restrict__ Wo,
    const float* __restrict__ bv,
    short* __restrict__ mt, short* __restrict__ wv2,
    float* __restrict__ bvec, float* __restrict__ bvp) {
  const int tid = threadIdx.x;
  const int lane = tid & 63, wid = tid >> 6;
  if (blockIdx.z == 2) {
    const int r0 = (blockIdx.y * 8 + blockIdx.x) * 16;
#pragma unroll
    for (int rr = 0; rr < 4; ++rr) {
      const int row = r0 + wid * 4 + rr;
      {
        const short* xr = wkT + (long)row * 1024 + lane * 16;
        short8v a0 = *reinterpret_cast<const short8v*>(xr);
        short8v a1 = *reinterpret_cast<const short8v*>(xr + 8);
        float s = 0.f;
#pragma unroll
        for (int j = 0; j < 8; ++j) s += bf2f(a0[j]) * bq[lane * 16 + j];
#pragma unroll
        for (int j = 0; j < 8; ++j) s += bf2f(a1[j]) * bq[lane * 16 + 8 + j];
#pragma unroll
        for (int off = 32; off; off >>= 1) s += __shfl_xor(s, off);
        if (lane == 0) bvec[row] = s * kExpScale;
      }
      {
        float s = 0.f;
#pragma unroll
        for (int j = 0; j < 16; ++j)
          s += Wo[(long)row * 1024 + j * 64 + lane] * bv[j * 64 + lane];
#pragma unroll
        for (int off = 32; off; off >>= 1) s += __shfl_xor(s, off);
        if (lane == 0) bvp[row] = s;
      }
    }
    return;
  }
  const short* A = blockIdx.z == 0 ? wkT : wob;
  const short* B = blockIdx.z == 0 ? wqT : wvT;
  short* C = blockIdx.z == 0 ? mt : wv2;
  const int bm = blockIdx.x * 128, bn = blockIdx.y * 128;
  f32x4 acc[4][4] = {};
  gemm_loop(A, B, 1024, 1024, 1024, bm, bn, acc);
  const int wr = wid >> 1, wc = wid & 1;
  const int fr = lane & 15, fq = lane >> 4;
#pragma unroll
  for (int n = 0; n < 4; ++n) {
    const int col = bn + wc * 64 + n * 16 + fr;
#pragma unroll
    for (int m = 0; m < 4; ++m) {
      const int row0 = bm + wr * 64 + m * 16 + fq * 4;
#pragma unroll
      for (int i = 0; i < 4; ++i)
        C[(long)(row0 + i) * 1024 + col] = f2bf(acc[m][n][i]);
    }
  }
}

// ---------- merged mid-stage launch, grid (64,8,3) ----------
__global__ __launch_bounds__(256, 3) void k_gemmTV(
    const short* __restrict__ xb, const short* __restrict__ mt,
    const short* __restrict__ wv2, const float* __restrict__ bvp,
    const float* __restrict__ bvec, short* __restrict__ T,
    short* __restrict__ vTp, float* __restrict__ w8) {
  const int tid = threadIdx.x;
  const int lane = tid & 63, wid = tid >> 6;
  if (blockIdx.z == 2) {
    const int rbase = (blockIdx.x * 8 + blockIdx.y) * 16;
#pragma unroll
    for (int rr = 0; rr < 4; ++rr) {
      const int row = rbase + wid * 4 + rr;
      const short* xr = xb + (long)row * 1024 + lane * 16;
      short8v a0 = *reinterpret_cast<const short8v*>(xr);
      short8v a1 = *reinterpret_cast<const short8v*>(xr + 8);
      float s = 0.f;
#pragma unroll
      for (int j = 0; j < 8; ++j) s += bf2f(a0[j]) * bvec[lane * 16 + j];
#pragma unroll
      for (int j = 0; j < 8; ++j) s += bf2f(a1[j]) * bvec[lane * 16 + 8 + j];
#pragma unroll
      for (int off = 32; off; off >>= 1) s += __shfl_xor(s, off);
      if (lane == 0) w8[row] = s;
    }
    return;
  }
  const short *A, *B; const float* bias; short* C; int ldC, bm, bn;
  if (blockIdx.z == 0) {
    A = xb; B = mt; bias = nullptr; C = T; ldC = 1024;
    bm = blockIdx.x * 128; bn = blockIdx.y * 128;
  } else {
    A = wv2; B = xb; bias = bvp; C = vTp; ldC = 8192;
    bm = blockIdx.y * 128; bn = blockIdx.x * 128;
  }
  f32x4 acc[4][4] = {};
  gemm_loop(A, B, 1024, 1024, 1024, bm, bn, acc);
  const int wr = wid >> 1, wc = wid & 1;
  const int fr = lane & 15, fq = lane >> 4;
#pragma unroll
  for (int n = 0; n < 4; ++n) {
    const int col = bn + wc * 64 + n * 16 + fr;
#pragma unroll
    for (int m = 0; m < 4; ++m) {
      const int row0 = bm + wr * 64 + m * 16 + fq * 4;
#pragma unroll
      for (int i = 0; i < 4; ++i) {
        const float bvr = bias ? bias[row0 + i] : 0.f;
        C[(long)(row0 + i) * ldC + col] = f2bf(acc[m][n][i] + bvr);
      }
    }
  }
}

// ---------- 2-phase dbuf BMx256 GEMM (T3-minimum recipe), 512 thr = 8 waves ----
// waves 2M x 4N; per-wave (BM/2)x64; BK=64; dbuf LDS; stage(t+1) issued BEFORE
// compute of tile t; one __syncthreads per tile (implicit vmcnt/lgkm drain is
// the hazard fence — R6-proven). Perfect 256-block grids (1 blk/CU, no tail).
// MODE 3: exp2 epilogue + psum (scores, BM=256)
// MODE 4: f32 out + col-bias + row-scale 1/L from psum (PV, BM=128)
template <int BM, int MODE>
__global__ __launch_bounds__(512, 2) void k2ph(
    const short* __restrict__ A, const short* __restrict__ B,
    const float* __restrict__ b0p, float* __restrict__ b1p,
    void* __restrict__ C0,
    int K, int lda, int ldb, long sA, long sB, long sC, int ldC) {
  constexpr int MFR = BM / 32;                // A frags per wave (8 / 4)
  __shared__ __align__(16) short lsA[2][BM * 64];
  __shared__ __align__(16) short lsB[2][256 * 64];
  __shared__ float invL[128];
  const int tid = threadIdx.x;
  const int lane = tid & 63, wid = tid >> 6;
  const int wr = wid >> 2, wc = wid & 3;      // 2M x 4N
  const int fr = lane & 15, fq = lane >> 4;
  const int bm = blockIdx.x * BM, bn = blockIdx.y * 256;
  const int bz = blockIdx.z;
  const short* Ab = A + (long)bz * sA;
  const short* Bb = B + (long)bz * sB;
  const int nt = K >> 6;

  if constexpr (MODE == 4) {
    if (tid < 256) {
      const int row = tid >> 1, half = tid & 1;
      const float* pr = b1p + ((long)bz * 2048 + bm + row) * 32 + half * 16;
      float s = 0.f;
#pragma unroll
      for (int j = 0; j < 4; ++j) {
        float4v v = *reinterpret_cast<const float4v*>(pr + j * 4);
        s += v[0] + v[1] + v[2] + v[3];
      }
      s += __shfl_xor(s, 1);
      if (half == 0) invL[row] = 1.0f / s;
    }
  }

  auto stage = [&](int buf, int kt) {
#pragma unroll
    for (int c = 0; c < BM / 64; ++c) {       // A: BM*8 chunks
      const int idx = c * 512 + tid;
      const int row = idx >> 3, colh = (idx & 7) << 3;
      __builtin_amdgcn_global_load_lds(
          (const __attribute__((address_space(1))) void*)
              (Ab + (long)(bm + row) * lda + kt + colh),
          (__attribute__((address_space(3))) void*)&lsA[buf][idx * 8], 16, 0, 0);
    }
#pragma unroll
    for (int c = 0; c < 4; ++c) {             // B: 256*8 chunks
      const int idx = c * 512 + tid;
      const int row = idx >> 3, colh = (idx & 7) << 3;
      __builtin_amdgcn_global_load_lds(
          (const __attribute__((address_space(1))) void*)
              (Bb + (long)(bn + row) * ldb + kt + colh),
          (__attribute__((address_space(3))) void*)&lsB[buf][idx * 8], 16, 0, 0);
    }
  };

  f32x4 acc[MFR][4] = {};

  stage(0, 0);
  __syncthreads();
  for (int t = 0; t < nt; ++t) {
    const int cur = t & 1;
    if (t + 1 < nt) stage(cur ^ 1, (t + 1) << 6);
    const short* cA = lsA[cur];
    const short* cB = lsB[cur];
#pragma unroll
    for (int ks = 0; ks < 64; ks += 32) {
      bf16x8 a[MFR], b[4];
#pragma unroll
      for (int m = 0; m < MFR; ++m)
        a[m] = ld8(&cA[(wr * (BM / 2) + m * 16 + fr) * 64 + ks + fq * 8]);
#pragma unroll
      for (int n = 0; n < 4; ++n)
        b[n] = ld8(&cB[(wc * 64 + n * 16 + fr) * 64 + ks + fq * 8]);
#pragma unroll
      for (int m = 0; m < MFR; ++m)
#pragma unroll
        for (int n = 0; n < 4; ++n)
          acc[m][n] = __builtin_amdgcn_mfma_f32_16x16x32_bf16(a[m], b[n], acc[m][n], 0, 0, 0);
    }
    __syncthreads();   // drains staged loads (vmcnt 0) + releases buf reuse
  }

  if constexpr (MODE == 3) {
    short* O = (short*)C0 + (long)bz * sC;
    float wv[4];
#pragma unroll
    for (int n = 0; n < 4; ++n)
      wv[n] = b0p[(long)bz * 2048 + bn + wc * 64 + n * 16 + fr];
#pragma unroll
    for (int m = 0; m < MFR; ++m) {
#pragma unroll
      for (int i = 0; i < 4; ++i) {
        const int row = bm + wr * (BM / 2) + m * 16 + fq * 4 + i;
        float rs = 0.f;
#pragma unroll
        for (int n = 0; n < 4; ++n) {
          float e = exp2f(acc[m][n][i] + wv[n]);
          O[(long)row * ldC + bn + wc * 64 + n * 16 + fr] = f2bf(e);
          rs += e;
        }
        rs += __shfl_xor(rs, 1); rs += __shfl_xor(rs, 2);
        rs += __shfl_xor(rs, 4); rs += __shfl_xor(rs, 8);
        if (fr == 0)
          b1p[((long)bz * 2048 + row) * 32 + (bn >> 6) + wc] = rs;
      }
    }
  } else {
#pragma unroll
    for (int n = 0; n < 4; ++n) {
      const int coll = wc * 64 + n * 16 + fr;
#pragma unroll
      for (int m = 0; m < MFR; ++m) {
        const int rl0 = wr * (BM / 2) + m * 16 + fq * 4;
#pragma unroll
        for (int i = 0; i < 4; ++i) {
          const long row = bm + rl0 + i, col = bn + coll;
          float* O = (float*)C0 + (long)bz * sC;
          O[row * ldC + col] = acc[m][n][i] * invL[rl0 + i] + b0p[col];
        }
      }
    }
  }
}

// ---------- launcher ----------
extern "C" void kernel_launch(void* const* d_in, const int* in_sizes, int n_in,
                              void* d_out, int out_size, void* d_ws, size_t ws_size,
                              hipStream_t stream) {
  const float* x  = (const float*)d_in[0];
  const float* Wq = (const float*)d_in[1];
  const float* bq = (const float*)d_in[2];
  const float* Wk = (const float*)d_in[3];
  // bk: provably no effect (softmax row-shift invariance) — unused.
  const float* Wv = (const float*)d_in[5];
  const float* bv = (const float*)d_in[6];
  const float* Wo = (const float*)d_in[7];
  const float* bo = (const float*)d_in[8];

  char* ws = (char*)d_ws;
  short* xb   = (short*)ws; ws += 8192L * 1024 * 2;     // x bf16
  short* wkT  = (short*)ws; ws += 1024L * 1024 * 2;     // Wk^T bf16
  short* wob  = (short*)ws; ws += 1024L * 1024 * 2;     // Wo bf16
  short* wqT  = (short*)ws; ws += 1024L * 1024 * 2;     // c*Wq^T bf16
  short* wvT  = (short*)ws; ws += 1024L * 1024 * 2;     // Wv^T bf16
  short* mt   = (short*)ws; ws += 1024L * 1024 * 2;     // Mt = Wk^T*(cWq)
  short* wv2  = (short*)ws; ws += 1024L * 1024 * 2;     // Wv'' = Wo*Wv
  short* T    = (short*)ws; ws += 8192L * 1024 * 2;     // T = x*Mt^T (pre-scaled)
  short* vTp  = (short*)ws; ws += 1024L * 8192 * 2;     // V'^T [e][b*2048+s]
  short* Sc   = (short*)ws; ws += 4L * 2048 * 2048 * 2; // exp-scores
  float* psum = (float*)ws; ws += 4L * 2048 * 32 * 4;   // row partial sums
  float* w8   = (float*)ws; ws += 8192L * 4;            // w' = c*x*(Wk^T bq)
  float* bvec = (float*)ws; ws += 1024L * 4;            // c * Wk^T bq
  float* bvp  = (float*)ws; ws += 1024L * 4;            // bv' = Wo * bv

  dim3 b256(256), b512(512);
  k_cvt<<<2048, b256, 0, stream>>>(x, xb);
  k_wprep<<<dim3(16, 8, 4), b256, 0, stream>>>(
      Wk, Wq, Wv, Wo, wkT, wqT, wvT, wob);
  k_prep2<<<dim3(8, 8, 3), b256, 0, stream>>>(
      wkT, wqT, wob, wvT, bq, Wo, bv, mt, wv2, bvec, bvp);
  k_gemmTV<<<dim3(64, 8, 3), b256, 0, stream>>>(
      xb, mt, wv2, bvp, bvec, T, vTp, w8);
  // exp-scores[b] = exp2(T[b]*x[b]^T + w') + psum ; 256x256 2ph, 256 blocks
  k2ph<256, 3><<<dim3(8, 8, 4), b512, 0, stream>>>(
      T, xb, w8, psum, Sc,
      1024, 1024, 1024, 2048L * 1024, 2048L * 1024, 2048L * 2048, 2048);
  // out = (P_unnorm * V') / L + bo ; 128x256 2ph, 256 blocks
  k2ph<128, 4><<<dim3(16, 4, 4), b512, 0, stream>>>(
      Sc, vTp, bo, psum, (float*)d_out,
      2048, 2048, 8192, 2048L * 2048, 2048, 2048L * 1024, 1024);
}

// Round 14
// 187.714 us; speedup vs baseline: 1.2740x; 1.0452x over previous
//
#include <hip/hip_runtime.h>

typedef short  short4v __attribute__((ext_vector_type(4)));
typedef short  short8v __attribute__((ext_vector_type(8)));
typedef __bf16 bf16x8  __attribute__((ext_vector_type(8)));
typedef float  f32x4   __attribute__((ext_vector_type(4)));
typedef float  float4v __attribute__((ext_vector_type(4)));

__device__ __forceinline__ short f2bf(float f) {
  unsigned u = __builtin_bit_cast(unsigned, f);
  u += 0x7fffu + ((u >> 16) & 1u);   // RNE
  return (short)(u >> 16);
}
__device__ __forceinline__ float bf2f(short h) {
  unsigned u = ((unsigned)(unsigned short)h) << 16;
  return __builtin_bit_cast(float, u);
}
__device__ __forceinline__ bf16x8 ld8(const short* p) {
  return __builtin_bit_cast(bf16x8, *reinterpret_cast<const short8v*>(p));
}

__constant__ const float kExpScale = 0.04508422f;   // log2(e)/32

// ---------- fp32 -> bf16 convert (x): 2048 blocks x 4 strided float4 ----------
__global__ __launch_bounds__(256) void k_cvt(const float* __restrict__ in,
                                             short* __restrict__ out) {
  const int i = blockIdx.x * 256 + threadIdx.x;
#pragma unroll
  for (int j = 0; j < 4; ++j) {
    const long g = (long)i + (long)j * 524288;
    float4v v = *reinterpret_cast<const float4v*>(in + g * 4);
    short4v o;
    o[0] = f2bf(v[0]); o[1] = f2bf(v[1]); o[2] = f2bf(v[2]); o[3] = f2bf(v[3]);
    *reinterpret_cast<short4v*>(out + g * 4) = o;
  }
}

// ---------- weight prep, 128x64 tiles, grid (16,8,4) ----------
__global__ __launch_bounds__(256) void k_wprep(const float* __restrict__ i0,
    const float* __restrict__ i1, const float* __restrict__ i2,
    const float* __restrict__ i3, short* __restrict__ o0, short* __restrict__ o1,
    short* __restrict__ o2, short* __restrict__ o3) {
  const int z = blockIdx.z;
  const float* in = z == 0 ? i0 : z == 1 ? i1 : z == 2 ? i2 : i3;
  short* out = z == 0 ? o0 : z == 1 ? o1 : z == 2 ? o2 : o3;
  const float sc = (z == 1) ? kExpScale : 1.0f;
  const int tid = threadIdx.x;
  const int c0 = blockIdx.x << 6;
  const int r0 = blockIdx.y << 7;
  if (z == 3) {
#pragma unroll
    for (int j = 0; j < 8; ++j) {
      int idx = j * 256 + tid;
      int r = idx >> 4, c4 = (idx & 15) << 2;
      float4v v = *reinterpret_cast<const float4v*>(in + (long)(r0 + r) * 1024 + c0 + c4);
      short4v o;
      o[0] = f2bf(v[0]); o[1] = f2bf(v[1]); o[2] = f2bf(v[2]); o[3] = f2bf(v[3]);
      *reinterpret_cast<short4v*>(out + (long)(r0 + r) * 1024 + c0 + c4) = o;
    }
    return;
  }
  __shared__ float tile[128][65];
#pragma unroll
  for (int j = 0; j < 8; ++j) {
    int idx = j * 256 + tid;
    int r = idx >> 4, c4 = (idx & 15) << 2;
    float4v v = *reinterpret_cast<const float4v*>(in + (long)(r0 + r) * 1024 + c0 + c4);
    tile[r][c4 + 0] = v[0] * sc; tile[r][c4 + 1] = v[1] * sc;
    tile[r][c4 + 2] = v[2] * sc; tile[r][c4 + 3] = v[3] * sc;
  }
  __syncthreads();
#pragma unroll
  for (int j = 0; j < 8; ++j) {
    int idx = j * 256 + tid;
    int rO = idx >> 5, g4 = (idx & 31) << 2;
    short4v o;
    o[0] = f2bf(tile[g4 + 0][rO]); o[1] = f2bf(tile[g4 + 1][rO]);
    o[2] = f2bf(tile[g4 + 2][rO]); o[3] = f2bf(tile[g4 + 3][rO]);
    *reinterpret_cast<short4v*>(out + (long)(c0 + rO) * 1024 + r0 + g4) = o;
  }
}

// ---------- m97 core loop (4 waves, single-buffer, 128x128) ----------
__device__ __forceinline__ void gemm_loop(const short* __restrict__ Ab,
    const short* __restrict__ Bb, int K, int lda, int ldb, int bm, int bn,
    f32x4 (&acc)[4][4]) {
  __shared__ __align__(16) short lsA[128 * 64];
  __shared__ __align__(16) short lsB[128 * 64];
  const int tid = threadIdx.x;
  const int lane = tid & 63, wid = tid >> 6;
  const int wr = wid >> 1, wc = wid & 1;
  const int fr = lane & 15, fq = lane >> 4;
  for (int kt = 0; kt < K; kt += 64) {
    __syncthreads();
#pragma unroll
    for (int c = 0; c < 4; ++c) {
      const int idx = c * 256 + tid;
      const int row = idx >> 3, colh = (idx & 7) << 3;
      const short* ga = Ab + (long)(bm + row) * lda + kt + colh;
      const short* gb = Bb + (long)(bn + row) * ldb + kt + colh;
      __builtin_amdgcn_global_load_lds(
          (const __attribute__((address_space(1))) void*)ga,
          (__attribute__((address_space(3))) void*)&lsA[idx * 8], 16, 0, 0);
      __builtin_amdgcn_global_load_lds(
          (const __attribute__((address_space(1))) void*)gb,
          (__attribute__((address_space(3))) void*)&lsB[idx * 8], 16, 0, 0);
    }
    __syncthreads();
#pragma unroll
    for (int ks = 0; ks < 64; ks += 32) {
      bf16x8 a[4], b[4];
#pragma unroll
      for (int m = 0; m < 4; ++m)
        a[m] = ld8(&lsA[(wr * 64 + m * 16 + fr) * 64 + ks + fq * 8]);
#pragma unroll
      for (int n = 0; n < 4; ++n)
        b[n] = ld8(&lsB[(wc * 64 + n * 16 + fr) * 64 + ks + fq * 8]);
#pragma unroll
      for (int m = 0; m < 4; ++m)
#pragma unroll
        for (int n = 0; n < 4; ++n)
          acc[m][n] = __builtin_amdgcn_mfma_f32_16x16x32_bf16(a[m], b[n], acc[m][n], 0, 0, 0);
    }
  }
}

// ---------- prep2: grid (8,8,3) — tiny GEMMs + vector preps ----------
__global__ __launch_bounds__(256, 3) void k_prep2(
    const short* __restrict__ wkT, const short* __restrict__ wqT,
    const short* __restrict__ wob, const short* __restrict__ wvT,
    const float* __restrict__ bq, const float* __restrict__ Wo,
    const float* __restrict__ bv,
    short* __restrict__ mt, short* __restrict__ wv2,
    float* __restrict__ bvec, float* __restrict__ bvp) {
  const int tid = threadIdx.x;
  const int lane = tid & 63, wid = tid >> 6;
  if (blockIdx.z == 2) {
    const int r0 = (blockIdx.y * 8 + blockIdx.x) * 16;
#pragma unroll
    for (int rr = 0; rr < 4; ++rr) {
      const int row = r0 + wid * 4 + rr;
      {
        const short* xr = wkT + (long)row * 1024 + lane * 16;
        short8v a0 = *reinterpret_cast<const short8v*>(xr);
        short8v a1 = *reinterpret_cast<const short8v*>(xr + 8);
        float s = 0.f;
#pragma unroll
        for (int j = 0; j < 8; ++j) s += bf2f(a0[j]) * bq[lane * 16 + j];
#pragma unroll
        for (int j = 0; j < 8; ++j) s += bf2f(a1[j]) * bq[lane * 16 + 8 + j];
#pragma unroll
        for (int off = 32; off; off >>= 1) s += __shfl_xor(s, off);
        if (lane == 0) bvec[row] = s * kExpScale;
      }
      {
        float s = 0.f;
#pragma unroll
        for (int j = 0; j < 16; ++j)
          s += Wo[(long)row * 1024 + j * 64 + lane] * bv[j * 64 + lane];
#pragma unroll
        for (int off = 32; off; off >>= 1) s += __shfl_xor(s, off);
        if (lane == 0) bvp[row] = s;
      }
    }
    return;
  }
  const short* A = blockIdx.z == 0 ? wkT : wob;
  const short* B = blockIdx.z == 0 ? wqT : wvT;
  short* C = blockIdx.z == 0 ? mt : wv2;
  const int bm = blockIdx.x * 128, bn = blockIdx.y * 128;
  f32x4 acc[4][4] = {};
  gemm_loop(A, B, 1024, 1024, 1024, bm, bn, acc);
  const int wr = wid >> 1, wc = wid & 1;
  const int fr = lane & 15, fq = lane >> 4;
#pragma unroll
  for (int n = 0; n < 4; ++n) {
    const int col = bn + wc * 64 + n * 16 + fr;
#pragma unroll
    for (int m = 0; m < 4; ++m) {
      const int row0 = bm + wr * 64 + m * 16 + fq * 4;
#pragma unroll
      for (int i = 0; i < 4; ++i)
        C[(long)(row0 + i) * 1024 + col] = f2bf(acc[m][n][i]);
    }
  }
}

// ---------- merged mid-stage launch, grid (64,8,3) ----------
__global__ __launch_bounds__(256, 3) void k_gemmTV(
    const short* __restrict__ xb, const short* __restrict__ mt,
    const short* __restrict__ wv2, const float* __restrict__ bvp,
    const float* __restrict__ bvec, short* __restrict__ T,
    short* __restrict__ vTp, float* __restrict__ w8) {
  const int tid = threadIdx.x;
  const int lane = tid & 63, wid = tid >> 6;
  if (blockIdx.z == 2) {
    const int rbase = (blockIdx.x * 8 + blockIdx.y) * 16;
#pragma unroll
    for (int rr = 0; rr < 4; ++rr) {
      const int row = rbase + wid * 4 + rr;
      const short* xr = xb + (long)row * 1024 + lane * 16;
      short8v a0 = *reinterpret_cast<const short8v*>(xr);
      short8v a1 = *reinterpret_cast<const short8v*>(xr + 8);
      float s = 0.f;
#pragma unroll
      for (int j = 0; j < 8; ++j) s += bf2f(a0[j]) * bvec[lane * 16 + j];
#pragma unroll
      for (int j = 0; j < 8; ++j) s += bf2f(a1[j]) * bvec[lane * 16 + 8 + j];
#pragma unroll
      for (int off = 32; off; off >>= 1) s += __shfl_xor(s, off);
      if (lane == 0) w8[row] = s;
    }
    return;
  }
  const short *A, *B; const float* bias; short* C; int ldC, bm, bn;
  if (blockIdx.z == 0) {
    A = xb; B = mt; bias = nullptr; C = T; ldC = 1024;
    bm = blockIdx.x * 128; bn = blockIdx.y * 128;
  } else {
    A = wv2; B = xb; bias = bvp; C = vTp; ldC = 8192;
    bm = blockIdx.y * 128; bn = blockIdx.x * 128;
  }
  f32x4 acc[4][4] = {};
  gemm_loop(A, B, 1024, 1024, 1024, bm, bn, acc);
  const int wr = wid >> 1, wc = wid & 1;
  const int fr = lane & 15, fq = lane >> 4;
#pragma unroll
  for (int n = 0; n < 4; ++n) {
    const int col = bn + wc * 64 + n * 16 + fr;
#pragma unroll
    for (int m = 0; m < 4; ++m) {
      const int row0 = bm + wr * 64 + m * 16 + fq * 4;
#pragma unroll
      for (int i = 0; i < 4; ++i) {
        const float bvr = bias ? bias[row0 + i] : 0.f;
        C[(long)(row0 + i) * ldC + col] = f2bf(acc[m][n][i] + bvr);
      }
    }
  }
}

// ---------- scores: 128x256 single-buffer, 512 thr = 8 waves (2M x 4N) ----------
// grid (16,8,4) = 512 blocks; LDS 48.5KB -> 2 resident/CU = 16 waves issuing
// (staging-delivery-bound: depth is the lever). exp2 epilogue + psum.
__global__ __launch_bounds__(512, 2) void k_scores(
    const short* __restrict__ A, const short* __restrict__ B,
    const float* __restrict__ b0p, float* __restrict__ b1p,
    short* __restrict__ C0,
    int K, long sA, long sB, long sC, int ldC) {
  __shared__ __align__(16) short lsA[128 * 64];
  __shared__ __align__(16) short lsB[256 * 64];
  const int tid = threadIdx.x;
  const int lane = tid & 63, wid = tid >> 6;
  const int wr = wid >> 2, wc = wid & 3;       // 2M x 4N
  const int fr = lane & 15, fq = lane >> 4;
  const int bm = blockIdx.x * 128, bn = blockIdx.y * 256;
  const int bz = blockIdx.z;
  const short* Ab = A + (long)bz * sA;
  const short* Bb = B + (long)bz * sB;

  f32x4 acc[4][4] = {};

  for (int kt = 0; kt < K; kt += 64) {
    __syncthreads();
#pragma unroll
    for (int c = 0; c < 2; ++c) {              // A: 128*8 = 1024 chunks
      const int idx = c * 512 + tid;
      const int row = idx >> 3, colh = (idx & 7) << 3;
      __builtin_amdgcn_global_load_lds(
          (const __attribute__((address_space(1))) void*)
              (Ab + (long)(bm + row) * K + kt + colh),
          (__attribute__((address_space(3))) void*)&lsA[idx * 8], 16, 0, 0);
    }
#pragma unroll
    for (int c = 0; c < 4; ++c) {              // B: 256*8 = 2048 chunks
      const int idx = c * 512 + tid;
      const int row = idx >> 3, colh = (idx & 7) << 3;
      __builtin_amdgcn_global_load_lds(
          (const __attribute__((address_space(1))) void*)
              (Bb + (long)(bn + row) * K + kt + colh),
          (__attribute__((address_space(3))) void*)&lsB[idx * 8], 16, 0, 0);
    }
    __syncthreads();
#pragma unroll
    for (int ks = 0; ks < 64; ks += 32) {
      bf16x8 a[4], b[4];
#pragma unroll
      for (int m = 0; m < 4; ++m)
        a[m] = ld8(&lsA[(wr * 64 + m * 16 + fr) * 64 + ks + fq * 8]);
#pragma unroll
      for (int n = 0; n < 4; ++n)
        b[n] = ld8(&lsB[(wc * 64 + n * 16 + fr) * 64 + ks + fq * 8]);
#pragma unroll
      for (int m = 0; m < 4; ++m)
#pragma unroll
        for (int n = 0; n < 4; ++n)
          acc[m][n] = __builtin_amdgcn_mfma_f32_16x16x32_bf16(a[m], b[n], acc[m][n], 0, 0, 0);
    }
  }

  short* O = C0 + (long)bz * sC;
  float wv[4];
#pragma unroll
  for (int n = 0; n < 4; ++n)
    wv[n] = b0p[(long)bz * 2048 + bn + wc * 64 + n * 16 + fr];
#pragma unroll
  for (int m = 0; m < 4; ++m) {
#pragma unroll
    for (int i = 0; i < 4; ++i) {
      const int row = bm + wr * 64 + m * 16 + fq * 4 + i;
      float rs = 0.f;
#pragma unroll
      for (int n = 0; n < 4; ++n) {
        float e = exp2f(acc[m][n][i] + wv[n]);
        O[(long)row * ldC + bn + wc * 64 + n * 16 + fr] = f2bf(e);
        rs += e;
      }
      rs += __shfl_xor(rs, 1); rs += __shfl_xor(rs, 2);
      rs += __shfl_xor(rs, 4); rs += __shfl_xor(rs, 8);
      if (fr == 0)
        b1p[((long)bz * 2048 + row) * 32 + blockIdx.y * 4 + wc] = rs;
    }
  }
}

// ---------- PV: R12-proven 256-thr 128x128 single-buffer, MODE 4 ----------
__global__ __launch_bounds__(256, 3) void k_pv(
    const short* __restrict__ A, const short* __restrict__ B,
    const float* __restrict__ b0p, float* __restrict__ b1p,
    float* __restrict__ C0,
    int K, int lda, int ldb, long sA, long sB, long sC, int ldC) {
  __shared__ float invL[128];
  const int tid = threadIdx.x;
  const int lane = tid & 63, wid = tid >> 6;
  const int wr = wid >> 1, wc = wid & 1;
  const int fr = lane & 15, fq = lane >> 4;
  const int bm = blockIdx.x * 128, bn = blockIdx.y * 128;
  const int bz = blockIdx.z;

  {
    const int row = tid >> 1, half = tid & 1;
    const float* pr = b1p + ((long)bz * 2048 + bm + row) * 32 + half * 16;
    float s = 0.f;
#pragma unroll
    for (int j = 0; j < 4; ++j) {
      float4v v = *reinterpret_cast<const float4v*>(pr + j * 4);
      s += v[0] + v[1] + v[2] + v[3];
    }
    s += __shfl_xor(s, 1);
    if (half == 0) invL[row] = 1.0f / s;
  }

  f32x4 acc[4][4] = {};
  gemm_loop(A + (long)bz * sA, B + (long)bz * sB, K, lda, ldb, bm, bn, acc);

#pragma unroll
  for (int n = 0; n < 4; ++n) {
    const int coll = wc * 64 + n * 16 + fr;
#pragma unroll
    for (int m = 0; m < 4; ++m) {
      const int rl0 = wr * 64 + m * 16 + fq * 4;
#pragma unroll
      for (int i = 0; i < 4; ++i) {
        const long row = bm + rl0 + i, col = bn + coll;
        float* O = C0 + (long)bz * sC;
        O[row * ldC + col] = acc[m][n][i] * invL[rl0 + i] + b0p[col];
      }
    }
  }
}

// ---------- launcher ----------
extern "C" void kernel_launch(void* const* d_in, const int* in_sizes, int n_in,
                              void* d_out, int out_size, void* d_ws, size_t ws_size,
                              hipStream_t stream) {
  const float* x  = (const float*)d_in[0];
  const float* Wq = (const float*)d_in[1];
  const float* bq = (const float*)d_in[2];
  const float* Wk = (const float*)d_in[3];
  // bk: provably no effect (softmax row-shift invariance) — unused.
  const float* Wv = (const float*)d_in[5];
  const float* bv = (const float*)d_in[6];
  const float* Wo = (const float*)d_in[7];
  const float* bo = (const float*)d_in[8];

  char* ws = (char*)d_ws;
  short* xb   = (short*)ws; ws += 8192L * 1024 * 2;     // x bf16
  short* wkT  = (short*)ws; ws += 1024L * 1024 * 2;     // Wk^T bf16
  short* wob  = (short*)ws; ws += 1024L * 1024 * 2;     // Wo bf16
  short* wqT  = (short*)ws; ws += 1024L * 1024 * 2;     // c*Wq^T bf16
  short* wvT  = (short*)ws; ws += 1024L * 1024 * 2;     // Wv^T bf16
  short* mt   = (short*)ws; ws += 1024L * 1024 * 2;     // Mt = Wk^T*(cWq)
  short* wv2  = (short*)ws; ws += 1024L * 1024 * 2;     // Wv'' = Wo*Wv
  short* T    = (short*)ws; ws += 8192L * 1024 * 2;     // T = x*Mt^T (pre-scaled)
  short* vTp  = (short*)ws; ws += 1024L * 8192 * 2;     // V'^T [e][b*2048+s]
  short* Sc   = (short*)ws; ws += 4L * 2048 * 2048 * 2; // exp-scores
  float* psum = (float*)ws; ws += 4L * 2048 * 32 * 4;   // row partial sums
  float* w8   = (float*)ws; ws += 8192L * 4;            // w' = c*x*(Wk^T bq)
  float* bvec = (float*)ws; ws += 1024L * 4;            // c * Wk^T bq
  float* bvp  = (float*)ws; ws += 1024L * 4;            // bv' = Wo * bv

  dim3 b256(256), b512(512);
  k_cvt<<<2048, b256, 0, stream>>>(x, xb);
  k_wprep<<<dim3(16, 8, 4), b256, 0, stream>>>(
      Wk, Wq, Wv, Wo, wkT, wqT, wvT, wob);
  k_prep2<<<dim3(8, 8, 3), b256, 0, stream>>>(
      wkT, wqT, wob, wvT, bq, Wo, bv, mt, wv2, bvec, bvp);
  k_gemmTV<<<dim3(64, 8, 3), b256, 0, stream>>>(
      xb, mt, wv2, bvp, bvec, T, vTp, w8);
  // exp-scores: 128x256 single-buf, 512 blocks = 2 resident/CU
  k_scores<<<dim3(16, 8, 4), b512, 0, stream>>>(
      T, xb, w8, psum, Sc,
      1024, 2048L * 1024, 2048L * 1024, 2048L * 2048, 2048);
  // out = (P_unnorm * V') / L + bo ; 128x128 single-buf, 512 blocks, 3-res
  k_pv<<<dim3(16, 8, 4), b256, 0, stream>>>(
      Sc, vTp, bo, psum, (float*)d_out,
      2048, 2048, 8192, 2048L * 2048, 2048, 2048L * 1024, 1024);
}